// Round 1
// baseline (302.819 us; speedup 1.0000x reference)
//
#include <hip/hip_runtime.h>

// Masked causal MHA: B=2, S=2048, E=1024, H=16, D=64.
// ws layout (bf16/ushort): xb[4096*1024] | wqt|wkt|wvt|wot[1024*1024 each, [N][K]]
//   | Qh|Kh|Vh [b,h,s,d] | Vt [b,h,d,s] | Ob [4096][1024].  Total ~56 MB.

using f32x4  = __attribute__((ext_vector_type(4))) float;
using bf16x8 = __attribute__((ext_vector_type(8))) __bf16;
using u16x8  = __attribute__((ext_vector_type(8))) unsigned short;

__device__ __forceinline__ unsigned short f2bf(float f) {
  unsigned u = __float_as_uint(f);
  u += 0x7fff + ((u >> 16) & 1u);            // round-to-nearest-even
  return (unsigned short)(u >> 16);
}

__device__ __forceinline__ bf16x8 ld_bf8(const unsigned short* p) {
  return __builtin_bit_cast(bf16x8, *reinterpret_cast<const u16x8*>(p));
}

#define GLDS16(gp, lp)                                                        \
  __builtin_amdgcn_global_load_lds(                                           \
      (__attribute__((address_space(1))) void*)(gp),                          \
      (__attribute__((address_space(3))) void*)(lp), 16, 0, 0)

// ---------------------------------------------------------------- cast x
__global__ void cast_x_kernel(const float* __restrict__ src,
                              unsigned short* __restrict__ dst) {
  const int i = (blockIdx.x * 256 + threadIdx.x) * 4;
  const float4 v = *reinterpret_cast<const float4*>(src + i);
  ushort4 o;
  o.x = f2bf(v.x); o.y = f2bf(v.y); o.z = f2bf(v.z); o.w = f2bf(v.w);
  *reinterpret_cast<ushort4*>(dst + i) = o;
}

// --------------------------------------------- cast + transpose W -> [N][K]
__global__ void cast_wt_kernel(const float* __restrict__ w0, const float* __restrict__ w1,
                               const float* __restrict__ w2, const float* __restrict__ w3,
                               unsigned short* __restrict__ t0, unsigned short* __restrict__ t1,
                               unsigned short* __restrict__ t2, unsigned short* __restrict__ t3) {
  const float* src; unsigned short* dst;
  switch (blockIdx.z) {
    case 0:  src = w0; dst = t0; break;
    case 1:  src = w1; dst = t1; break;
    case 2:  src = w2; dst = t2; break;
    default: src = w3; dst = t3; break;
  }
  __shared__ float tile[64][65];
  const int n0 = blockIdx.x * 64, k0 = blockIdx.y * 64;
  const int t = threadIdx.x;
#pragma unroll
  for (int i = 0; i < 4; ++i) {               // load 64x64 fp32 tile, rows = k
    const int q = t + i * 256, r = q >> 4, c4 = q & 15;
    const float4 v = *reinterpret_cast<const float4*>(src + (k0 + r) * 1024 + n0 + c4 * 4);
    tile[r][c4 * 4 + 0] = v.x; tile[r][c4 * 4 + 1] = v.y;
    tile[r][c4 * 4 + 2] = v.z; tile[r][c4 * 4 + 3] = v.w;
  }
  __syncthreads();
#pragma unroll
  for (int i = 0; i < 4; ++i) {               // write Wt[n][k] bf16
    const int q = t + i * 256, n = q >> 4, c4 = q & 15;
    ushort4 o;
    o.x = f2bf(tile[c4 * 4 + 0][n]); o.y = f2bf(tile[c4 * 4 + 1][n]);
    o.z = f2bf(tile[c4 * 4 + 2][n]); o.w = f2bf(tile[c4 * 4 + 3][n]);
    *reinterpret_cast<ushort4*>(dst + (n0 + n) * 1024 + k0 + c4 * 4) = o;
  }
}

// ------------------------------------------------------------------- GEMM
// C[M=4096][N] = A[M][1024] @ Bt^T (+ bias). Bt is [N][K]. 128x128 tile, BK=64,
// 4 waves of 64x64. MODE 0: fused QKV, bf16 out scattered to [b,h,s,d].
// MODE 1: single weight, fp32 out.
template <int MODE>
__global__ __launch_bounds__(256, 2) void gemm128(
    const unsigned short* __restrict__ A,
    const unsigned short* __restrict__ BtQ, const unsigned short* __restrict__ BtK,
    const unsigned short* __restrict__ BtV,
    const float* __restrict__ biasQ, const float* __restrict__ biasK,
    const float* __restrict__ biasV,
    unsigned short* __restrict__ OQ, unsigned short* __restrict__ OK_,
    unsigned short* __restrict__ OV, float* __restrict__ OF) {
  __shared__ unsigned short As[128 * 64];
  __shared__ unsigned short Bs[128 * 64];

  const int mt = blockIdx.x, nt = blockIdx.y;
  const unsigned short* Bt; const float* bias;
  unsigned short* Obf = nullptr;
  int nloc0;
  if (MODE == 0) {
    const int which = nt >> 3;
    nloc0 = (nt & 7) * 128;
    Bt   = (which == 0) ? BtQ   : (which == 1) ? BtK   : BtV;
    bias = (which == 0) ? biasQ : (which == 1) ? biasK : biasV;
    Obf  = (which == 0) ? OQ    : (which == 1) ? OK_   : OV;
  } else {
    nloc0 = nt * 128;
    Bt = BtQ; bias = biasQ;
  }
  const int m0 = mt * 128;
  const int t = threadIdx.x;
  const int w = t >> 6, l = t & 63;
  const int wm = (w >> 1) * 64, wn = (w & 1) * 64;
  const int lr = l & 15, lg = l >> 4;

  f32x4 acc[4][4];
#pragma unroll
  for (int i = 0; i < 4; ++i)
#pragma unroll
    for (int j = 0; j < 4; ++j) acc[i][j] = f32x4{0.f, 0.f, 0.f, 0.f};

  for (int k0 = 0; k0 < 1024; k0 += 64) {
#pragma unroll
    for (int i = 0; i < 4; ++i) {             // stage A tile: [128 m][64 k]
      const int off = t * 16 + i * 4096;
      const int r = off >> 7, cb = off & 127;
      GLDS16(A + (m0 + r) * 1024 + k0 + (cb >> 1), ((char*)As) + off);
    }
#pragma unroll
    for (int i = 0; i < 4; ++i) {             // stage B tile: [128 n][64 k]
      const int off = t * 16 + i * 4096;
      const int r = off >> 7, cb = off & 127;
      GLDS16(Bt + (nloc0 + r) * 1024 + k0 + (cb >> 1), ((char*)Bs) + off);
    }
    __syncthreads();
#pragma unroll
    for (int kk = 0; kk < 2; ++kk) {
      bf16x8 af[4], bfr[4];
#pragma unroll
      for (int mi = 0; mi < 4; ++mi)
        af[mi] = ld_bf8(As + (wm + mi * 16 + lr) * 64 + kk * 32 + lg * 8);
#pragma unroll
      for (int ni = 0; ni < 4; ++ni)
        bfr[ni] = ld_bf8(Bs + (wn + ni * 16 + lr) * 64 + kk * 32 + lg * 8);
#pragma unroll
      for (int mi = 0; mi < 4; ++mi)
#pragma unroll
        for (int ni = 0; ni < 4; ++ni)
          acc[mi][ni] = __builtin_amdgcn_mfma_f32_16x16x32_bf16(af[mi], bfr[ni], acc[mi][ni], 0, 0, 0);
    }
    __syncthreads();
  }

#pragma unroll
  for (int ni = 0; ni < 4; ++ni) {
    const int n = nloc0 + wn + ni * 16 + lr;  // column within this weight
    const float bv = bias[n];
#pragma unroll
    for (int mi = 0; mi < 4; ++mi) {
#pragma unroll
      for (int r = 0; r < 4; ++r) {
        const int m = m0 + wm + mi * 16 + 4 * lg + r;
        const float v = acc[mi][ni][r] + bv;
        if (MODE == 0) {
          const int b = m >> 11, s = m & 2047;
          const int h = n >> 6,  d = n & 63;
          Obf[(((b * 16 + h) * 2048) + s) * 64 + d] = f2bf(v);
        } else {
          OF[m * 1024 + n] = v;
        }
      }
    }
  }
}

// ------------------------------------------- V [b,h,s,d] -> Vt [b,h,d,s]
__global__ void transpose_v_kernel(const unsigned short* __restrict__ Vh,
                                   unsigned short* __restrict__ Vt) {
  const int bh = blockIdx.y;
  const int s0 = blockIdx.x * 64;
  __shared__ unsigned short tile[64][72];
  const int t = threadIdx.x;
#pragma unroll
  for (int i = 0; i < 4; ++i) {
    const int q = t + i * 256, r = q >> 4, c4 = q & 15;
    const ushort4 v = *reinterpret_cast<const ushort4*>(Vh + ((size_t)bh * 2048 + s0 + r) * 64 + c4 * 4);
    tile[r][c4 * 4 + 0] = v.x; tile[r][c4 * 4 + 1] = v.y;
    tile[r][c4 * 4 + 2] = v.z; tile[r][c4 * 4 + 3] = v.w;
  }
  __syncthreads();
#pragma unroll
  for (int i = 0; i < 4; ++i) {
    const int q = t + i * 256, d = q >> 4, c4 = q & 15;
    ushort4 o;
    o.x = tile[c4 * 4 + 0][d]; o.y = tile[c4 * 4 + 1][d];
    o.z = tile[c4 * 4 + 2][d]; o.w = tile[c4 * 4 + 3][d];
    *reinterpret_cast<ushort4*>(Vt + ((size_t)bh * 64 + d) * 2048 + s0 + c4 * 4) = o;
  }
}

// ------------------------------------------------------- flash attention
// grid (qt=32, bh=32); 4 waves x 16 q-rows, KVBLK=64, causal, online softmax.
__global__ __launch_bounds__(256, 4) void attn_kernel(
    const unsigned short* __restrict__ Qh, const unsigned short* __restrict__ Kh,
    const unsigned short* __restrict__ Vt, unsigned short* __restrict__ Ob) {
  const int qt = blockIdx.x, bh = blockIdx.y;
  const int b = bh >> 4, h = bh & 15;
  const int t = threadIdx.x, w = t >> 6, l = t & 63;
  const int lr = l & 15, lg = l >> 4;
  const int qbase = qt * 64 + w * 16;

  __shared__ unsigned short Pl[4][16][72];   // per-wave P buffer (padded)

  const unsigned short* Qp = Qh + ((size_t)bh * 2048 + qbase + lr) * 64;
  const bf16x8 qf0 = ld_bf8(Qp + lg * 8);
  const bf16x8 qf1 = ld_bf8(Qp + 32 + lg * 8);

  f32x4 oacc[4];
#pragma unroll
  for (int i = 0; i < 4; ++i) oacc[i] = f32x4{0.f, 0.f, 0.f, 0.f};
  float mrun[4], lrun[4];
#pragma unroll
  for (int r = 0; r < 4; ++r) { mrun[r] = -1e30f; lrun[r] = 0.f; }

  const unsigned short* Kbase = Kh + (size_t)bh * 2048 * 64;
  const unsigned short* Vbase = Vt + (size_t)bh * 64 * 2048;
  const int kvend = qbase + 15;
  for (int kv0 = 0; kv0 <= kvend; kv0 += 64) {
    f32x4 sacc[4];
#pragma unroll
    for (int i = 0; i < 4; ++i) sacc[i] = f32x4{0.f, 0.f, 0.f, 0.f};
#pragma unroll
    for (int kf = 0; kf < 2; ++kf) {
      const bf16x8 qa = kf ? qf1 : qf0;
#pragma unroll
      for (int nf = 0; nf < 4; ++nf) {
        const bf16x8 kb = ld_bf8(Kbase + (size_t)(kv0 + nf * 16 + lr) * 64 + kf * 32 + lg * 8);
        sacc[nf] = __builtin_amdgcn_mfma_f32_16x16x32_bf16(qa, kb, sacc[nf], 0, 0, 0);
      }
    }
    // scale + causal mask + per-row max
    float mx[4];
#pragma unroll
    for (int r = 0; r < 4; ++r) mx[r] = -1e30f;
#pragma unroll
    for (int nf = 0; nf < 4; ++nf) {
      const int kv = kv0 + nf * 16 + lr;
#pragma unroll
      for (int r = 0; r < 4; ++r) {
        const int q = qbase + 4 * lg + r;
        float sv = sacc[nf][r] * 0.125f;
        sv = (kv > q) ? -1e30f : sv;
        sacc[nf][r] = sv;
        mx[r] = fmaxf(mx[r], sv);
      }
    }
#pragma unroll
    for (int dd = 1; dd < 16; dd <<= 1)
#pragma unroll
      for (int r = 0; r < 4; ++r) mx[r] = fmaxf(mx[r], __shfl_xor(mx[r], dd));

    float corr[4], rs[4];
#pragma unroll
    for (int r = 0; r < 4; ++r) {
      const float mnew = fmaxf(mrun[r], mx[r]);
      corr[r] = __expf(mrun[r] - mnew);
      mrun[r] = mnew;
      lrun[r] *= corr[r];
      rs[r] = 0.f;
    }
#pragma unroll
    for (int nf = 0; nf < 4; ++nf)
#pragma unroll
      for (int r = 0; r < 4; ++r) {
        const float p = __expf(sacc[nf][r] - mrun[r]);
        sacc[nf][r] = p;
        rs[r] += p;
      }
#pragma unroll
    for (int dd = 1; dd < 16; dd <<= 1)
#pragma unroll
      for (int r = 0; r < 4; ++r) rs[r] += __shfl_xor(rs[r], dd);
#pragma unroll
    for (int r = 0; r < 4; ++r) lrun[r] += rs[r];
#pragma unroll
    for (int i = 0; i < 4; ++i)
#pragma unroll
      for (int r = 0; r < 4; ++r) oacc[i][r] *= corr[r];

    // P (D-layout) -> LDS [q][kv] bf16, then read back as A-layout
#pragma unroll
    for (int nf = 0; nf < 4; ++nf)
#pragma unroll
      for (int r = 0; r < 4; ++r)
        Pl[w][4 * lg + r][nf * 16 + lr] = f2bf(sacc[nf][r]);

#pragma unroll
    for (int kf = 0; kf < 2; ++kf) {
      const bf16x8 pa = ld_bf8(&Pl[w][lr][kf * 32 + lg * 8]);
#pragma unroll
      for (int df = 0; df < 4; ++df) {
        const bf16x8 vb = ld_bf8(Vbase + (size_t)(df * 16 + lr) * 2048 + kv0 + kf * 32 + lg * 8);
        oacc[df] = __builtin_amdgcn_mfma_f32_16x16x32_bf16(pa, vb, oacc[df], 0, 0, 0);
      }
    }
  }

  float inv[4];
#pragma unroll
  for (int r = 0; r < 4; ++r) inv[r] = 1.f / lrun[r];
#pragma unroll
  for (int df = 0; df < 4; ++df) {
    const int d = df * 16 + lr;
#pragma unroll
    for (int r = 0; r < 4; ++r) {
      const int q = qbase + 4 * lg + r;
      Ob[((size_t)(b * 2048 + q)) * 1024 + h * 64 + d] = f2bf(oacc[df][r] * inv[r]);
    }
  }
}

// ------------------------------------------------------------------ launch
extern "C" void kernel_launch(void* const* d_in, const int* in_sizes, int n_in,
                              void* d_out, int out_size, void* d_ws, size_t ws_size,
                              hipStream_t stream) {
  const float* x  = (const float*)d_in[0];
  const float* Wq = (const float*)d_in[1];
  const float* bq = (const float*)d_in[2];
  const float* Wk = (const float*)d_in[3];
  const float* bk = (const float*)d_in[4];
  const float* Wv = (const float*)d_in[5];
  const float* bv = (const float*)d_in[6];
  const float* Wo = (const float*)d_in[7];
  const float* bo = (const float*)d_in[8];
  float* out = (float*)d_out;

  unsigned short* xb  = (unsigned short*)d_ws;          // 4096*1024
  unsigned short* wqt = xb  + 4096 * 1024;              // 1024*1024 each
  unsigned short* wkt = wqt + 1024 * 1024;
  unsigned short* wvt = wkt + 1024 * 1024;
  unsigned short* wot = wvt + 1024 * 1024;
  unsigned short* Qh  = wot + 1024 * 1024;              // [b,h,s,d]
  unsigned short* Kh  = Qh  + 4096 * 1024;
  unsigned short* Vh  = Kh  + 4096 * 1024;
  unsigned short* Vt  = Vh  + 4096 * 1024;              // [b,h,d,s]
  unsigned short* Ob  = Vt  + 4096 * 1024;              // [4096][1024]

  cast_x_kernel<<<4096, 256, 0, stream>>>(x, xb);
  cast_wt_kernel<<<dim3(16, 16, 4), 256, 0, stream>>>(Wq, Wk, Wv, Wo, wqt, wkt, wvt, wot);
  gemm128<0><<<dim3(32, 24), 256, 0, stream>>>(xb, wqt, wkt, wvt, bq, bk, bv,
                                               Qh, Kh, Vh, nullptr);
  transpose_v_kernel<<<dim3(32, 32), 256, 0, stream>>>(Vh, Vt);
  attn_kernel<<<dim3(32, 32), 256, 0, stream>>>(Qh, Kh, Vt, Ob);
  gemm128<1><<<dim3(32, 8), 256, 0, stream>>>(Ob, wot, nullptr, nullptr, bo, nullptr, nullptr,
                                              nullptr, nullptr, nullptr, out);
}

// Round 2
// 183.923 us; speedup vs baseline: 1.6464x; 1.6464x over previous
//
#include <hip/hip_runtime.h>

// Masked causal MHA: B=2, S=2048, E=1024, H=16, D=64.
// ws layout (bf16/ushort): xb[4096*1024] | wqt|wkt|wvt|wot[1024*1024 each, [N][K]]
//   | Qh|Kh|Vh [b,h,s,d] | Vt [b,h,d,s] | Ob [4096][1024].  Total ~56 MB.

using f32x4  = __attribute__((ext_vector_type(4))) float;
using bf16x8 = __attribute__((ext_vector_type(8))) __bf16;
using u16x8  = __attribute__((ext_vector_type(8))) unsigned short;

__device__ __forceinline__ unsigned short f2bf(float f) {
  unsigned u = __float_as_uint(f);
  u += 0x7fff + ((u >> 16) & 1u);            // round-to-nearest-even
  return (unsigned short)(u >> 16);
}

__device__ __forceinline__ unsigned short bfc(float f) {   // HW cvt
  __bf16 h = (__bf16)f;
  return __builtin_bit_cast(unsigned short, h);
}

__device__ __forceinline__ bf16x8 ld_bf8(const unsigned short* p) {
  return __builtin_bit_cast(bf16x8, *reinterpret_cast<const u16x8*>(p));
}

#define GLDS16(gp, lp)                                                        \
  __builtin_amdgcn_global_load_lds(                                           \
      (__attribute__((address_space(1))) void*)(gp),                          \
      (__attribute__((address_space(3))) void*)(lp), 16, 0, 0)

// ---------------------------------------------------------------- cast x
__global__ void cast_x_kernel(const float* __restrict__ src,
                              unsigned short* __restrict__ dst) {
  const int i = (blockIdx.x * 256 + threadIdx.x) * 4;
  const float4 v = *reinterpret_cast<const float4*>(src + i);
  ushort4 o;
  o.x = f2bf(v.x); o.y = f2bf(v.y); o.z = f2bf(v.z); o.w = f2bf(v.w);
  *reinterpret_cast<ushort4*>(dst + i) = o;
}

// --------------------------------------------- cast + transpose W -> [N][K]
__global__ void cast_wt_kernel(const float* __restrict__ w0, const float* __restrict__ w1,
                               const float* __restrict__ w2, const float* __restrict__ w3,
                               unsigned short* __restrict__ t0, unsigned short* __restrict__ t1,
                               unsigned short* __restrict__ t2, unsigned short* __restrict__ t3) {
  const float* src; unsigned short* dst;
  switch (blockIdx.z) {
    case 0:  src = w0; dst = t0; break;
    case 1:  src = w1; dst = t1; break;
    case 2:  src = w2; dst = t2; break;
    default: src = w3; dst = t3; break;
  }
  __shared__ float tile[64][65];
  const int n0 = blockIdx.x * 64, k0 = blockIdx.y * 64;
  const int t = threadIdx.x;
#pragma unroll
  for (int i = 0; i < 4; ++i) {               // load 64x64 fp32 tile, rows = k
    const int q = t + i * 256, r = q >> 4, c4 = q & 15;
    const float4 v = *reinterpret_cast<const float4*>(src + (k0 + r) * 1024 + n0 + c4 * 4);
    tile[r][c4 * 4 + 0] = v.x; tile[r][c4 * 4 + 1] = v.y;
    tile[r][c4 * 4 + 2] = v.z; tile[r][c4 * 4 + 3] = v.w;
  }
  __syncthreads();
#pragma unroll
  for (int i = 0; i < 4; ++i) {               // write Wt[n][k] bf16
    const int q = t + i * 256, n = q >> 4, c4 = q & 15;
    ushort4 o;
    o.x = f2bf(tile[c4 * 4 + 0][n]); o.y = f2bf(tile[c4 * 4 + 1][n]);
    o.z = f2bf(tile[c4 * 4 + 2][n]); o.w = f2bf(tile[c4 * 4 + 3][n]);
    *reinterpret_cast<ushort4*>(dst + (n0 + n) * 1024 + k0 + c4 * 4) = o;
  }
}

// ------------------------------------------------------------------- GEMM
// C[M=4096][N] = A[M][1024] @ Bt^T (+ bias). Bt is [N][K]. 128x128 tile, BK=64,
// 4 waves of 64x64. MODE 0: fused QKV, bf16 out scattered to [b,h,s,d].
// MODE 1: single weight, fp32 out.
template <int MODE>
__global__ __launch_bounds__(256, 2) void gemm128(
    const unsigned short* __restrict__ A,
    const unsigned short* __restrict__ BtQ, const unsigned short* __restrict__ BtK,
    const unsigned short* __restrict__ BtV,
    const float* __restrict__ biasQ, const float* __restrict__ biasK,
    const float* __restrict__ biasV,
    unsigned short* __restrict__ OQ, unsigned short* __restrict__ OK_,
    unsigned short* __restrict__ OV, float* __restrict__ OF) {
  __shared__ unsigned short As[128 * 64];
  __shared__ unsigned short Bs[128 * 64];

  const int mt = blockIdx.x, nt = blockIdx.y;
  const unsigned short* Bt; const float* bias;
  unsigned short* Obf = nullptr;
  int nloc0;
  if (MODE == 0) {
    const int which = nt >> 3;
    nloc0 = (nt & 7) * 128;
    Bt   = (which == 0) ? BtQ   : (which == 1) ? BtK   : BtV;
    bias = (which == 0) ? biasQ : (which == 1) ? biasK : biasV;
    Obf  = (which == 0) ? OQ    : (which == 1) ? OK_   : OV;
  } else {
    nloc0 = nt * 128;
    Bt = BtQ; bias = biasQ;
  }
  const int m0 = mt * 128;
  const int t = threadIdx.x;
  const int w = t >> 6, l = t & 63;
  const int wm = (w >> 1) * 64, wn = (w & 1) * 64;
  const int lr = l & 15, lg = l >> 4;

  f32x4 acc[4][4];
#pragma unroll
  for (int i = 0; i < 4; ++i)
#pragma unroll
    for (int j = 0; j < 4; ++j) acc[i][j] = f32x4{0.f, 0.f, 0.f, 0.f};

  for (int k0 = 0; k0 < 1024; k0 += 64) {
#pragma unroll
    for (int i = 0; i < 4; ++i) {             // stage A tile: [128 m][64 k]
      const int off = t * 16 + i * 4096;
      const int r = off >> 7, cb = off & 127;
      GLDS16(A + (m0 + r) * 1024 + k0 + (cb >> 1), ((char*)As) + off);
    }
#pragma unroll
    for (int i = 0; i < 4; ++i) {             // stage B tile: [128 n][64 k]
      const int off = t * 16 + i * 4096;
      const int r = off >> 7, cb = off & 127;
      GLDS16(Bt + (nloc0 + r) * 1024 + k0 + (cb >> 1), ((char*)Bs) + off);
    }
    __syncthreads();
#pragma unroll
    for (int kk = 0; kk < 2; ++kk) {
      bf16x8 af[4], bfr[4];
#pragma unroll
      for (int mi = 0; mi < 4; ++mi)
        af[mi] = ld_bf8(As + (wm + mi * 16 + lr) * 64 + kk * 32 + lg * 8);
#pragma unroll
      for (int ni = 0; ni < 4; ++ni)
        bfr[ni] = ld_bf8(Bs + (wn + ni * 16 + lr) * 64 + kk * 32 + lg * 8);
#pragma unroll
      for (int mi = 0; mi < 4; ++mi)
#pragma unroll
        for (int ni = 0; ni < 4; ++ni)
          acc[mi][ni] = __builtin_amdgcn_mfma_f32_16x16x32_bf16(af[mi], bfr[ni], acc[mi][ni], 0, 0, 0);
    }
    __syncthreads();
  }

#pragma unroll
  for (int ni = 0; ni < 4; ++ni) {
    const int n = nloc0 + wn + ni * 16 + lr;  // column within this weight
    const float bv = bias[n];
#pragma unroll
    for (int mi = 0; mi < 4; ++mi) {
#pragma unroll
      for (int r = 0; r < 4; ++r) {
        const int m = m0 + wm + mi * 16 + 4 * lg + r;
        const float v = acc[mi][ni][r] + bv;
        if (MODE == 0) {
          const int b = m >> 11, s = m & 2047;
          const int h = n >> 6,  d = n & 63;
          Obf[(((b * 16 + h) * 2048) + s) * 64 + d] = f2bf(v);
        } else {
          OF[m * 1024 + n] = v;
        }
      }
    }
  }
}

// ------------------------------------------- V [b,h,s,d] -> Vt [b,h,d,s]
__global__ void transpose_v_kernel(const unsigned short* __restrict__ Vh,
                                   unsigned short* __restrict__ Vt) {
  const int bh = blockIdx.y;
  const int s0 = blockIdx.x * 64;
  __shared__ unsigned short tile[64][72];
  const int t = threadIdx.x;
#pragma unroll
  for (int i = 0; i < 4; ++i) {
    const int q = t + i * 256, r = q >> 4, c4 = q & 15;
    const ushort4 v = *reinterpret_cast<const ushort4*>(Vh + ((size_t)bh * 2048 + s0 + r) * 64 + c4 * 4);
    tile[r][c4 * 4 + 0] = v.x; tile[r][c4 * 4 + 1] = v.y;
    tile[r][c4 * 4 + 2] = v.z; tile[r][c4 * 4 + 3] = v.w;
  }
  __syncthreads();
#pragma unroll
  for (int i = 0; i < 4; ++i) {
    const int q = t + i * 256, d = q >> 4, c4 = q & 15;
    ushort4 o;
    o.x = tile[c4 * 4 + 0][d]; o.y = tile[c4 * 4 + 1][d];
    o.z = tile[c4 * 4 + 2][d]; o.w = tile[c4 * 4 + 3][d];
    *reinterpret_cast<ushort4*>(Vt + ((size_t)bh * 64 + d) * 2048 + s0 + c4 * 4) = o;
  }
}

// ------------------------------------------------------- flash attention v2
// grid: 512 blocks (longest-first). Block = 128 q rows, 4 waves x 32 rows
// (two 16-row frags at w*16 and 64+w*16 so all waves share the KV range).
// K/V tiles (64x64) double-buffered in LDS via global_load_lds with T2-style
// XOR swizzle (pre-swizzled global source chunk, linear LDS dest, swizzled
// ds_read). One __syncthreads per tile (T3 minimum 2-phase recipe).
__global__ __launch_bounds__(256, 2) void attn_kernel(
    const unsigned short* __restrict__ Qh, const unsigned short* __restrict__ Kh,
    const unsigned short* __restrict__ Vt, unsigned short* __restrict__ Ob) {
  const int g = blockIdx.x;
  const int qt = 15 - (g >> 5);              // longest blocks dispatch first
  const int bh = g & 31;
  const int b = bh >> 4, h = bh & 15;
  const int t = threadIdx.x, w = t >> 6, l = t & 63;
  const int lr = l & 15, lg = l >> 4;

  __shared__ unsigned short Kb[2][4096];     // [64 kv][64 d], swizzled
  __shared__ unsigned short Vb[2][4096];     // [64 d][64 kv], swizzled
  __shared__ unsigned short Pl[4][2048];     // per-wave [32 q][64 kv], swizzled

  const unsigned short* Kbase = Kh + (size_t)bh * (2048 * 64);
  const unsigned short* Vbase = Vt + (size_t)bh * (64 * 2048);

  const int qb0 = qt * 128 + w * 16;
  const int qb1 = qb0 + 64;

  const unsigned short* Qp0 = Qh + ((size_t)bh * 2048 + qb0 + lr) * 64;
  const unsigned short* Qp1 = Qh + ((size_t)bh * 2048 + qb1 + lr) * 64;
  bf16x8 qf[2][2];
  qf[0][0] = ld_bf8(Qp0 + lg * 8);
  qf[0][1] = ld_bf8(Qp0 + 32 + lg * 8);
  qf[1][0] = ld_bf8(Qp1 + lg * 8);
  qf[1][1] = ld_bf8(Qp1 + 32 + lg * 8);

  f32x4 oacc[2][4];
  float mrun[2][4], lrun[2][4];
#pragma unroll
  for (int f = 0; f < 2; ++f) {
#pragma unroll
    for (int i = 0; i < 4; ++i) oacc[f][i] = f32x4{0.f, 0.f, 0.f, 0.f};
#pragma unroll
    for (int r = 0; r < 4; ++r) { mrun[f][r] = -3e38f; lrun[f][r] = 0.f; }
  }

  auto stage = [&](int kv0, int bi) {
#pragma unroll
    for (int p = 0; p < 2; ++p) {
      const int o = t * 16 + p * 4096;       // linear byte offset in 8KB tile
      const int row = o >> 7;
      const int scb = (o & 127) ^ ((row & 7) << 4);   // pre-swizzled src col
      GLDS16(Kbase + (size_t)(kv0 + row) * 64 + (scb >> 1), ((char*)Kb[bi]) + o);
      GLDS16(Vbase + (size_t)row * 2048 + kv0 + (scb >> 1), ((char*)Vb[bi]) + o);
    }
  };

  const int nt = 2 * qt + 2;
  stage(0, 0);
  __syncthreads();

  const float SC = 0.18033688f;              // 0.125 * log2(e)

  auto smax = [&](f32x4* s, const int qb, const int fi, const int kv0) {
    float mx[4] = {-3e38f, -3e38f, -3e38f, -3e38f};
#pragma unroll
    for (int nf = 0; nf < 4; ++nf) {
      const int kv = kv0 + nf * 16 + lr;
#pragma unroll
      for (int r = 0; r < 4; ++r) {
        const int q = qb + 4 * lg + r;
        float sv = s[nf][r] * SC;
        sv = (kv > q) ? -3e38f : sv;
        s[nf][r] = sv;
        mx[r] = fmaxf(mx[r], sv);
      }
    }
#pragma unroll
    for (int dd = 1; dd < 16; dd <<= 1)
#pragma unroll
      for (int r = 0; r < 4; ++r) mx[r] = fmaxf(mx[r], __shfl_xor(mx[r], dd));
    float corr[4];
#pragma unroll
    for (int r = 0; r < 4; ++r) {
      const float mnew = fmaxf(mrun[fi][r], mx[r]);
      corr[r] = exp2f(mrun[fi][r] - mnew);
      mrun[fi][r] = mnew;
    }
    float rs[4] = {0.f, 0.f, 0.f, 0.f};
#pragma unroll
    for (int nf = 0; nf < 4; ++nf)
#pragma unroll
      for (int r = 0; r < 4; ++r) {
        const float p = exp2f(s[nf][r] - mrun[fi][r]);
        const int prow = fi * 16 + 4 * lg + r;
        Pl[w][prow * 64 + ((nf * 16 + lr) ^ ((prow & 7) << 3))] = bfc(p);
        rs[r] += p;
      }
#pragma unroll
    for (int dd = 1; dd < 16; dd <<= 1)
#pragma unroll
      for (int r = 0; r < 4; ++r) rs[r] += __shfl_xor(rs[r], dd);
#pragma unroll
    for (int r = 0; r < 4; ++r) lrun[fi][r] = lrun[fi][r] * corr[r] + rs[r];
#pragma unroll
    for (int df = 0; df < 4; ++df)
#pragma unroll
      for (int r = 0; r < 4; ++r) oacc[fi][df][r] *= corr[r];
  };

  for (int ti = 0; ti < nt; ++ti) {
    const int cur = ti & 1;
    const int kv0 = ti * 64;
    if (ti + 1 < nt) stage((ti + 1) * 64, cur ^ 1);

    const bool a0 = (kv0 <= qb0 + 15);       // frag1 is always active

    // ---- QK^T, K loads shared across both frags
    f32x4 s0[4], s1[4];
#pragma unroll
    for (int i = 0; i < 4; ++i) { s0[i] = f32x4{0.f,0.f,0.f,0.f}; s1[i] = f32x4{0.f,0.f,0.f,0.f}; }
#pragma unroll
    for (int kf = 0; kf < 2; ++kf) {
#pragma unroll
      for (int nf = 0; nf < 4; ++nf) {
        const int row = nf * 16 + lr;
        const int col = (kf * 32 + lg * 8) ^ ((row & 7) << 3);
        const bf16x8 kb = ld_bf8(&Kb[cur][row * 64 + col]);
        if (a0) s0[nf] = __builtin_amdgcn_mfma_f32_16x16x32_bf16(qf[0][kf], kb, s0[nf], 0, 0, 0);
        s1[nf] = __builtin_amdgcn_mfma_f32_16x16x32_bf16(qf[1][kf], kb, s1[nf], 0, 0, 0);
      }
    }

    if (a0) smax(s0, qb0, 0, kv0);
    smax(s1, qb1, 1, kv0);

    // ---- PV, V loads shared across both frags
#pragma unroll
    for (int kf = 0; kf < 2; ++kf) {
      bf16x8 vb[4];
#pragma unroll
      for (int df = 0; df < 4; ++df) {
        const int vrow = df * 16 + lr;
        const int vcol = (kf * 32 + lg * 8) ^ ((vrow & 7) << 3);
        vb[df] = ld_bf8(&Vb[cur][vrow * 64 + vcol]);
      }
      if (a0) {
        const int pcol = (kf * 32 + lg * 8) ^ ((lr & 7) << 3);
        const bf16x8 pa = ld_bf8(&Pl[w][lr * 64 + pcol]);
#pragma unroll
        for (int df = 0; df < 4; ++df)
          oacc[0][df] = __builtin_amdgcn_mfma_f32_16x16x32_bf16(pa, vb[df], oacc[0][df], 0, 0, 0);
      }
      {
        const int prow = 16 + lr;
        const int pcol = (kf * 32 + lg * 8) ^ ((prow & 7) << 3);
        const bf16x8 pa = ld_bf8(&Pl[w][prow * 64 + pcol]);
#pragma unroll
        for (int df = 0; df < 4; ++df)
          oacc[1][df] = __builtin_amdgcn_mfma_f32_16x16x32_bf16(pa, vb[df], oacc[1][df], 0, 0, 0);
      }
    }
    __syncthreads();                         // drains prefetch + guards buffers
  }

#pragma unroll
  for (int fi = 0; fi < 2; ++fi) {
    const int qb = fi ? qb1 : qb0;
    float inv[4];
#pragma unroll
    for (int r = 0; r < 4; ++r) inv[r] = 1.f / lrun[fi][r];
#pragma unroll
    for (int df = 0; df < 4; ++df) {
      const int d = df * 16 + lr;
#pragma unroll
      for (int r = 0; r < 4; ++r) {
        const int q = qb + 4 * lg + r;
        Ob[((size_t)(b * 2048 + q)) * 1024 + h * 64 + d] = bfc(oacc[fi][df][r] * inv[r]);
      }
    }
  }
}

// ------------------------------------------------------------------ launch
extern "C" void kernel_launch(void* const* d_in, const int* in_sizes, int n_in,
                              void* d_out, int out_size, void* d_ws, size_t ws_size,
                              hipStream_t stream) {
  const float* x  = (const float*)d_in[0];
  const float* Wq = (const float*)d_in[1];
  const float* bq = (const float*)d_in[2];
  const float* Wk = (const float*)d_in[3];
  const float* bk = (const float*)d_in[4];
  const float* Wv = (const float*)d_in[5];
  const float* bv = (const float*)d_in[6];
  const float* Wo = (const float*)d_in[7];
  const float* bo = (const float*)d_in[8];
  float* out = (float*)d_out;

  unsigned short* xb  = (unsigned short*)d_ws;          // 4096*1024
  unsigned short* wqt = xb  + 4096 * 1024;              // 1024*1024 each
  unsigned short* wkt = wqt + 1024 * 1024;
  unsigned short* wvt = wkt + 1024 * 1024;
  unsigned short* wot = wvt + 1024 * 1024;
  unsigned short* Qh  = wot + 1024 * 1024;              // [b,h,s,d]
  unsigned short* Kh  = Qh  + 4096 * 1024;
  unsigned short* Vh  = Kh  + 4096 * 1024;
  unsigned short* Vt  = Vh  + 4096 * 1024;              // [b,h,d,s]
  unsigned short* Ob  = Vt  + 4096 * 1024;              // [4096][1024]

  cast_x_kernel<<<4096, 256, 0, stream>>>(x, xb);
  cast_wt_kernel<<<dim3(16, 16, 4), 256, 0, stream>>>(Wq, Wk, Wv, Wo, wqt, wkt, wvt, wot);
  gemm128<0><<<dim3(32, 24), 256, 0, stream>>>(xb, wqt, wkt, wvt, bq, bk, bv,
                                               Qh, Kh, Vh, nullptr);
  transpose_v_kernel<<<dim3(32, 32), 256, 0, stream>>>(Vh, Vt);
  attn_kernel<<<512, 256, 0, stream>>>(Qh, Kh, Vt, Ob);
  gemm128<1><<<dim3(32, 8), 256, 0, stream>>>(Ob, wot, nullptr, nullptr, bo, nullptr, nullptr,
                                              nullptr, nullptr, nullptr, out);
}

// Round 3
// 165.195 us; speedup vs baseline: 1.8331x; 1.1134x over previous
//
#include <hip/hip_runtime.h>

// Masked causal MHA: B=2, S=2048, E=1024, H=16, D=64.
// ws layout (bf16/ushort): xb[4096*1024] | wqt|wkt|wvt|wot[1024*1024 each, [N][K]]
//   | Qh|Kh|Vh [b,h,s,d] | Vt [b,h,d,s] | Ob [4096][1024].  Total ~56 MB.

using f32x4  = __attribute__((ext_vector_type(4))) float;
using bf16x8 = __attribute__((ext_vector_type(8))) __bf16;
using u16x8  = __attribute__((ext_vector_type(8))) unsigned short;
using u32x4  = __attribute__((ext_vector_type(4))) unsigned int;

__device__ __forceinline__ unsigned short f2bf(float f) {
  unsigned u = __float_as_uint(f);
  u += 0x7fff + ((u >> 16) & 1u);            // round-to-nearest-even
  return (unsigned short)(u >> 16);
}

__device__ __forceinline__ unsigned short bfc(float f) {   // HW cvt
  __bf16 h = (__bf16)f;
  return __builtin_bit_cast(unsigned short, h);
}

__device__ __forceinline__ bf16x8 ld_bf8(const unsigned short* p) {
  return __builtin_bit_cast(bf16x8, *reinterpret_cast<const u16x8*>(p));
}

#define GLDS16(gp, lp)                                                        \
  __builtin_amdgcn_global_load_lds(                                           \
      (__attribute__((address_space(1))) void*)(gp),                          \
      (__attribute__((address_space(3))) void*)(lp), 16, 0, 0)

// ---------------------------------------------------------------- cast x
__global__ void cast_x_kernel(const float* __restrict__ src,
                              unsigned short* __restrict__ dst) {
  const int i = (blockIdx.x * 256 + threadIdx.x) * 4;
  const float4 v = *reinterpret_cast<const float4*>(src + i);
  ushort4 o;
  o.x = f2bf(v.x); o.y = f2bf(v.y); o.z = f2bf(v.z); o.w = f2bf(v.w);
  *reinterpret_cast<ushort4*>(dst + i) = o;
}

// --------------------------------------------- cast + transpose W -> [N][K]
__global__ void cast_wt_kernel(const float* __restrict__ w0, const float* __restrict__ w1,
                               const float* __restrict__ w2, const float* __restrict__ w3,
                               unsigned short* __restrict__ t0, unsigned short* __restrict__ t1,
                               unsigned short* __restrict__ t2, unsigned short* __restrict__ t3) {
  const float* src; unsigned short* dst;
  switch (blockIdx.z) {
    case 0:  src = w0; dst = t0; break;
    case 1:  src = w1; dst = t1; break;
    case 2:  src = w2; dst = t2; break;
    default: src = w3; dst = t3; break;
  }
  __shared__ float tile[64][65];
  const int n0 = blockIdx.x * 64, k0 = blockIdx.y * 64;
  const int t = threadIdx.x;
#pragma unroll
  for (int i = 0; i < 4; ++i) {               // load 64x64 fp32 tile, rows = k
    const int q = t + i * 256, r = q >> 4, c4 = q & 15;
    const float4 v = *reinterpret_cast<const float4*>(src + (k0 + r) * 1024 + n0 + c4 * 4);
    tile[r][c4 * 4 + 0] = v.x; tile[r][c4 * 4 + 1] = v.y;
    tile[r][c4 * 4 + 2] = v.z; tile[r][c4 * 4 + 3] = v.w;
  }
  __syncthreads();
#pragma unroll
  for (int i = 0; i < 4; ++i) {               // write Wt[n][k] bf16
    const int q = t + i * 256, n = q >> 4, c4 = q & 15;
    ushort4 o;
    o.x = f2bf(tile[c4 * 4 + 0][n]); o.y = f2bf(tile[c4 * 4 + 1][n]);
    o.z = f2bf(tile[c4 * 4 + 2][n]); o.w = f2bf(tile[c4 * 4 + 3][n]);
    *reinterpret_cast<ushort4*>(dst + (n0 + n) * 1024 + k0 + c4 * 4) = o;
  }
}

// ------------------------------------------------------------------- GEMM
// C[M=4096][N] = A[M][1024] @ Bt^T (+ bias). Bt is [N][K]. 128x128 tile, BK=64,
// 4 waves of 64x64. MODE 0: fused QKV (Q pre-scaled by 0.125*log2e), bf16 out
// scattered to [b,h,s,d]. MODE 1: single weight, fp32 out.
template <int MODE>
__global__ __launch_bounds__(256, 2) void gemm128(
    const unsigned short* __restrict__ A,
    const unsigned short* __restrict__ BtQ, const unsigned short* __restrict__ BtK,
    const unsigned short* __restrict__ BtV,
    const float* __restrict__ biasQ, const float* __restrict__ biasK,
    const float* __restrict__ biasV,
    unsigned short* __restrict__ OQ, unsigned short* __restrict__ OK_,
    unsigned short* __restrict__ OV, float* __restrict__ OF) {
  __shared__ unsigned short As[128 * 64];
  __shared__ unsigned short Bs[128 * 64];

  const int mt = blockIdx.x, nt = blockIdx.y;
  const unsigned short* Bt; const float* bias;
  unsigned short* Obf = nullptr;
  int nloc0;
  float scl = 1.0f;
  if (MODE == 0) {
    const int which = nt >> 3;
    nloc0 = (nt & 7) * 128;
    Bt   = (which == 0) ? BtQ   : (which == 1) ? BtK   : BtV;
    bias = (which == 0) ? biasQ : (which == 1) ? biasK : biasV;
    Obf  = (which == 0) ? OQ    : (which == 1) ? OK_   : OV;
    if (which == 0) scl = 0.18033688f;        // 0.125 * log2(e)
  } else {
    nloc0 = nt * 128;
    Bt = BtQ; bias = biasQ;
  }
  const int m0 = mt * 128;
  const int t = threadIdx.x;
  const int w = t >> 6, l = t & 63;
  const int wm = (w >> 1) * 64, wn = (w & 1) * 64;
  const int lr = l & 15, lg = l >> 4;

  f32x4 acc[4][4];
#pragma unroll
  for (int i = 0; i < 4; ++i)
#pragma unroll
    for (int j = 0; j < 4; ++j) acc[i][j] = f32x4{0.f, 0.f, 0.f, 0.f};

  for (int k0 = 0; k0 < 1024; k0 += 64) {
#pragma unroll
    for (int i = 0; i < 4; ++i) {             // stage A tile: [128 m][64 k]
      const int off = t * 16 + i * 4096;
      const int r = off >> 7, cb = off & 127;
      GLDS16(A + (m0 + r) * 1024 + k0 + (cb >> 1), ((char*)As) + off);
    }
#pragma unroll
    for (int i = 0; i < 4; ++i) {             // stage B tile: [128 n][64 k]
      const int off = t * 16 + i * 4096;
      const int r = off >> 7, cb = off & 127;
      GLDS16(Bt + (nloc0 + r) * 1024 + k0 + (cb >> 1), ((char*)Bs) + off);
    }
    __syncthreads();
#pragma unroll
    for (int kk = 0; kk < 2; ++kk) {
      bf16x8 af[4], bfr[4];
#pragma unroll
      for (int mi = 0; mi < 4; ++mi)
        af[mi] = ld_bf8(As + (wm + mi * 16 + lr) * 64 + kk * 32 + lg * 8);
#pragma unroll
      for (int ni = 0; ni < 4; ++ni)
        bfr[ni] = ld_bf8(Bs + (wn + ni * 16 + lr) * 64 + kk * 32 + lg * 8);
#pragma unroll
      for (int mi = 0; mi < 4; ++mi)
#pragma unroll
        for (int ni = 0; ni < 4; ++ni)
          acc[mi][ni] = __builtin_amdgcn_mfma_f32_16x16x32_bf16(af[mi], bfr[ni], acc[mi][ni], 0, 0, 0);
    }
    __syncthreads();
  }

#pragma unroll
  for (int ni = 0; ni < 4; ++ni) {
    const int n = nloc0 + wn + ni * 16 + lr;  // column within this weight
    const float bv = bias[n];
#pragma unroll
    for (int mi = 0; mi < 4; ++mi) {
#pragma unroll
      for (int r = 0; r < 4; ++r) {
        const int m = m0 + wm + mi * 16 + 4 * lg + r;
        const float v = (acc[mi][ni][r] + bv) * scl;
        if (MODE == 0) {
          const int b = m >> 11, s = m & 2047;
          const int h = n >> 6,  d = n & 63;
          Obf[(((b * 16 + h) * 2048) + s) * 64 + d] = f2bf(v);
        } else {
          OF[m * 1024 + n] = v;
        }
      }
    }
  }
}

// ------------------------------------------- V [b,h,s,d] -> Vt [b,h,d,s]
__global__ void transpose_v_kernel(const unsigned short* __restrict__ Vh,
                                   unsigned short* __restrict__ Vt) {
  const int bh = blockIdx.y;
  const int s0 = blockIdx.x * 64;
  __shared__ unsigned short tile[64][72];
  const int t = threadIdx.x;
#pragma unroll
  for (int i = 0; i < 4; ++i) {
    const int q = t + i * 256, r = q >> 4, c4 = q & 15;
    const ushort4 v = *reinterpret_cast<const ushort4*>(Vh + ((size_t)bh * 2048 + s0 + r) * 64 + c4 * 4);
    tile[r][c4 * 4 + 0] = v.x; tile[r][c4 * 4 + 1] = v.y;
    tile[r][c4 * 4 + 2] = v.z; tile[r][c4 * 4 + 3] = v.w;
  }
  __syncthreads();
#pragma unroll
  for (int i = 0; i < 4; ++i) {
    const int q = t + i * 256, d = q >> 4, c4 = q & 15;
    ushort4 o;
    o.x = tile[c4 * 4 + 0][d]; o.y = tile[c4 * 4 + 1][d];
    o.z = tile[c4 * 4 + 2][d]; o.w = tile[c4 * 4 + 3][d];
    *reinterpret_cast<ushort4*>(Vt + ((size_t)bh * 64 + d) * 2048 + s0 + c4 * 4) = o;
  }
}

// ------------------------------------------------------- flash attention v3
// Swapped QK^T (S^T layout: q = lane&15, kv in-lane) -> in-register softmax,
// P redistributed to PV B-operand via cvt_pk + bpermute; PV computes O^T.
// Block = 128 q rows, 4 waves x (2 frags of 16 rows). KV tiles 64, dbuf LDS,
// swizzled staging. Grid paired so every CU gets ~constant work.
__global__ __launch_bounds__(256, 2) void attn_kernel(
    const unsigned short* __restrict__ Qh, const unsigned short* __restrict__ Kh,
    const unsigned short* __restrict__ Vt, unsigned short* __restrict__ Ob) {
  const int g = blockIdx.x;
  const int qt = (g < 256) ? (15 - (g >> 5)) : ((g - 256) >> 5);
  const int bh = g & 31;
  const int b = bh >> 4, h = bh & 15;
  const int t = threadIdx.x, w = t >> 6, l = t & 63;
  const int lr = l & 15, lg = l >> 4;
  const int sl0 = lr + 32 * (lg & 1);        // pack-shuffle source lanes
  const int sl1 = sl0 + 16;
  const bool hi2 = (l & 32) != 0;

  __shared__ unsigned short Kb[2][4096];     // [64 kv][64 d], swizzled
  __shared__ unsigned short Vb[2][4096];     // [64 d][64 kv], swizzled

  const unsigned short* Kbase = Kh + (size_t)bh * (2048 * 64);
  const unsigned short* Vbase = Vt + (size_t)bh * (64 * 2048);

  const int qb0 = qt * 128 + w * 16;
  const int qb1 = qb0 + 64;

  const unsigned short* Qp0 = Qh + ((size_t)bh * 2048 + qb0 + lr) * 64;
  const unsigned short* Qp1 = Qh + ((size_t)bh * 2048 + qb1 + lr) * 64;
  bf16x8 qf[2][2];
  qf[0][0] = ld_bf8(Qp0 + lg * 8);
  qf[0][1] = ld_bf8(Qp0 + 32 + lg * 8);
  qf[1][0] = ld_bf8(Qp1 + lg * 8);
  qf[1][1] = ld_bf8(Qp1 + 32 + lg * 8);

  f32x4 oacc[2][4];                          // O^T: lane q=qb+lr, d=df*16+4lg+r
#pragma unroll
  for (int f = 0; f < 2; ++f)
#pragma unroll
    for (int i = 0; i < 4; ++i) oacc[f][i] = f32x4{0.f, 0.f, 0.f, 0.f};
  float mrun[2] = {-3e38f, -3e38f};
  float lrun[2] = {0.f, 0.f};

  auto stage = [&](int kv0, int bi) {
#pragma unroll
    for (int p = 0; p < 2; ++p) {
      const int o = t * 16 + p * 4096;       // linear byte offset in 8KB tile
      const int row = o >> 7;
      const int scb = (o & 127) ^ ((row & 7) << 4);   // pre-swizzled src col
      GLDS16(Kbase + (size_t)(kv0 + row) * 64 + (scb >> 1), ((char*)Kb[bi]) + o);
      GLDS16(Vbase + (size_t)row * 2048 + kv0 + (scb >> 1), ((char*)Vb[bi]) + o);
    }
  };

  // softmax on S^T frag + pack P^T B-operand fragments (all in registers)
  auto softpack = [&](f32x4* s, int qb, float& mref, float& lref, f32x4* oa,
                      bf16x8* pa, int kv0) {
    if (kv0 + 63 > qb) {                     // masked (diagonal) tile only
#pragma unroll
      for (int nf = 0; nf < 4; ++nf) {
        const int kv = kv0 + nf * 16 + 4 * lg;
#pragma unroll
        for (int r = 0; r < 4; ++r)
          if (kv + r > qb + lr) s[nf][r] = -3e38f;
      }
    }
    float mx = -3e38f;
#pragma unroll
    for (int nf = 0; nf < 4; ++nf)
#pragma unroll
      for (int r = 0; r < 4; ++r) mx = fmaxf(mx, s[nf][r]);
    mx = fmaxf(mx, __shfl_xor(mx, 16));
    mx = fmaxf(mx, __shfl_xor(mx, 32));
    if (!__all(mx <= mref + 8.f)) {          // defer-max (T13)
      const float mnew = fmaxf(mref, mx);
      const float corr = exp2f(mref - mnew);
      mref = mnew;
      lref *= corr;
#pragma unroll
      for (int df = 0; df < 4; ++df)
#pragma unroll
        for (int r = 0; r < 4; ++r) oa[df][r] *= corr;
    }
    float rs = 0.f;
#pragma unroll
    for (int nf = 0; nf < 4; ++nf)
#pragma unroll
      for (int r = 0; r < 4; ++r) {
        const float p = exp2f(s[nf][r] - mref);
        s[nf][r] = p;
        rs += p;
      }
    rs += __shfl_xor(rs, 16);
    rs += __shfl_xor(rs, 32);
    lref += rs;
    unsigned wpk[4][2];
#pragma unroll
    for (int nf = 0; nf < 4; ++nf) {
      asm("v_cvt_pk_bf16_f32 %0, %1, %2" : "=v"(wpk[nf][0]) : "v"(s[nf][0]), "v"(s[nf][1]));
      asm("v_cvt_pk_bf16_f32 %0, %1, %2" : "=v"(wpk[nf][1]) : "v"(s[nf][2]), "v"(s[nf][3]));
    }
#pragma unroll
    for (int kf = 0; kf < 2; ++kf) {
      const unsigned a0w = __shfl(wpk[2 * kf][0], sl0), b0w = __shfl(wpk[2 * kf + 1][0], sl0);
      const unsigned a1w = __shfl(wpk[2 * kf][1], sl0), b1w = __shfl(wpk[2 * kf + 1][1], sl0);
      const unsigned a2w = __shfl(wpk[2 * kf][0], sl1), b2w = __shfl(wpk[2 * kf + 1][0], sl1);
      const unsigned a3w = __shfl(wpk[2 * kf][1], sl1), b3w = __shfl(wpk[2 * kf + 1][1], sl1);
      u32x4 uu;
      uu[0] = hi2 ? b0w : a0w;
      uu[1] = hi2 ? b1w : a1w;
      uu[2] = hi2 ? b2w : a2w;
      uu[3] = hi2 ? b3w : a3w;
      pa[kf] = __builtin_bit_cast(bf16x8, uu);
    }
  };

  const int nt = 2 * qt + 2;
  stage(0, 0);
  __syncthreads();

  for (int ti = 0; ti < nt; ++ti) {
    const int cur = ti & 1;
    const int kv0 = ti * 64;
    if (ti + 1 < nt) stage((ti + 1) * 64, cur ^ 1);

    const bool a0 = (kv0 <= qb0 + 15);       // frag1 always active

    // ---- QK^T (swapped: S^T = K . Q^T), K loads shared across frags
    f32x4 s0[4], s1[4];
#pragma unroll
    for (int i = 0; i < 4; ++i) { s0[i] = f32x4{0.f,0.f,0.f,0.f}; s1[i] = f32x4{0.f,0.f,0.f,0.f}; }
    __builtin_amdgcn_s_setprio(1);
#pragma unroll
    for (int kf = 0; kf < 2; ++kf) {
#pragma unroll
      for (int nf = 0; nf < 4; ++nf) {
        const int row = nf * 16 + lr;
        const int col = (kf * 32 + lg * 8) ^ ((row & 7) << 3);
        const bf16x8 kb = ld_bf8(&Kb[cur][row * 64 + col]);
        if (a0) s0[nf] = __builtin_amdgcn_mfma_f32_16x16x32_bf16(kb, qf[0][kf], s0[nf], 0, 0, 0);
        s1[nf] = __builtin_amdgcn_mfma_f32_16x16x32_bf16(kb, qf[1][kf], s1[nf], 0, 0, 0);
      }
    }
    __builtin_amdgcn_s_setprio(0);

    bf16x8 pa0[2], pa1[2];
    if (a0) softpack(s0, qb0, mrun[0], lrun[0], oacc[0], pa0, kv0);
    softpack(s1, qb1, mrun[1], lrun[1], oacc[1], pa1, kv0);

    // ---- PV: O^T += V^T . P^T, V loads shared across frags
    __builtin_amdgcn_s_setprio(1);
#pragma unroll
    for (int kf = 0; kf < 2; ++kf) {
#pragma unroll
      for (int df = 0; df < 4; ++df) {
        const int vrow = df * 16 + lr;
        const int vcol = (kf * 32 + lg * 8) ^ ((vrow & 7) << 3);
        const bf16x8 vb = ld_bf8(&Vb[cur][vrow * 64 + vcol]);
        if (a0) oacc[0][df] = __builtin_amdgcn_mfma_f32_16x16x32_bf16(vb, pa0[kf], oacc[0][df], 0, 0, 0);
        oacc[1][df] = __builtin_amdgcn_mfma_f32_16x16x32_bf16(vb, pa1[kf], oacc[1][df], 0, 0, 0);
      }
    }
    __builtin_amdgcn_s_setprio(0);
    __syncthreads();                         // drains prefetch + guards buffers
  }

#pragma unroll
  for (int fi = 0; fi < 2; ++fi) {
    const int qb = fi ? qb1 : qb0;
    const float inv = 1.f / lrun[fi];
    const int q = qb + lr;
#pragma unroll
    for (int df = 0; df < 4; ++df) {
      ushort4 o4;
      o4.x = bfc(oacc[fi][df][0] * inv);
      o4.y = bfc(oacc[fi][df][1] * inv);
      o4.z = bfc(oacc[fi][df][2] * inv);
      o4.w = bfc(oacc[fi][df][3] * inv);
      *reinterpret_cast<ushort4*>(
          &Ob[((size_t)(b * 2048 + q)) * 1024 + h * 64 + df * 16 + 4 * lg]) = o4;
    }
  }
}

// ------------------------------------------------------------------ launch
extern "C" void kernel_launch(void* const* d_in, const int* in_sizes, int n_in,
                              void* d_out, int out_size, void* d_ws, size_t ws_size,
                              hipStream_t stream) {
  const float* x  = (const float*)d_in[0];
  const float* Wq = (const float*)d_in[1];
  const float* bq = (const float*)d_in[2];
  const float* Wk = (const float*)d_in[3];
  const float* bk = (const float*)d_in[4];
  const float* Wv = (const float*)d_in[5];
  const float* bv = (const float*)d_in[6];
  const float* Wo = (const float*)d_in[7];
  const float* bo = (const float*)d_in[8];
  float* out = (float*)d_out;

  unsigned short* xb  = (unsigned short*)d_ws;          // 4096*1024
  unsigned short* wqt = xb  + 4096 * 1024;              // 1024*1024 each
  unsigned short* wkt = wqt + 1024 * 1024;
  unsigned short* wvt = wkt + 1024 * 1024;
  unsigned short* wot = wvt + 1024 * 1024;
  unsigned short* Qh  = wot + 1024 * 1024;              // [b,h,s,d]
  unsigned short* Kh  = Qh  + 4096 * 1024;
  unsigned short* Vh  = Kh  + 4096 * 1024;
  unsigned short* Vt  = Vh  + 4096 * 1024;              // [b,h,d,s]
  unsigned short* Ob  = Vt  + 4096 * 1024;              // [4096][1024]

  cast_x_kernel<<<4096, 256, 0, stream>>>(x, xb);
  cast_wt_kernel<<<dim3(16, 16, 4), 256, 0, stream>>>(Wq, Wk, Wv, Wo, wqt, wkt, wvt, wot);
  gemm128<0><<<dim3(32, 24), 256, 0, stream>>>(xb, wqt, wkt, wvt, bq, bk, bv,
                                               Qh, Kh, Vh, nullptr);
  transpose_v_kernel<<<dim3(32, 32), 256, 0, stream>>>(Vh, Vt);
  attn_kernel<<<512, 256, 0, stream>>>(Qh, Kh, Vt, Ob);
  gemm128<1><<<dim3(32, 8), 256, 0, stream>>>(Ob, wot, nullptr, nullptr, bo, nullptr, nullptr,
                                              nullptr, nullptr, nullptr, out);
}

// Round 4
// 153.064 us; speedup vs baseline: 1.9784x; 1.0793x over previous
//
#include <hip/hip_runtime.h>

// Masked causal MHA: B=2, S=2048, E=1024, H=16, D=64.
// ws layout (bf16/ushort): xb[4096*1024] | wqt|wkt|wvt|wot[1024*1024 each, [N][K]]
//   | Qh|Kh|Vh [b,h,s,d] | Vt [b,h,d,s] | Ob [4096][1024].  Total ~56 MB.

using f32x4  = __attribute__((ext_vector_type(4))) float;
using bf16x8 = __attribute__((ext_vector_type(8))) __bf16;
using u16x8  = __attribute__((ext_vector_type(8))) unsigned short;
using u32x4  = __attribute__((ext_vector_type(4))) unsigned int;

__device__ __forceinline__ unsigned short f2bf(float f) {
  unsigned u = __float_as_uint(f);
  u += 0x7fff + ((u >> 16) & 1u);            // round-to-nearest-even
  return (unsigned short)(u >> 16);
}

__device__ __forceinline__ unsigned short bfc(float f) {   // HW cvt
  __bf16 h = (__bf16)f;
  return __builtin_bit_cast(unsigned short, h);
}

__device__ __forceinline__ bf16x8 ld_bf8(const unsigned short* p) {
  return __builtin_bit_cast(bf16x8, *reinterpret_cast<const u16x8*>(p));
}

#define GLDS16(gp, lp)                                                        \
  __builtin_amdgcn_global_load_lds(                                           \
      (__attribute__((address_space(1))) void*)(gp),                          \
      (__attribute__((address_space(3))) void*)(lp), 16, 0, 0)

// ---------------------------------------------------------------- cast x
__global__ void cast_x_kernel(const float* __restrict__ src,
                              unsigned short* __restrict__ dst) {
  const int i = (blockIdx.x * 256 + threadIdx.x) * 4;
  const float4 v = *reinterpret_cast<const float4*>(src + i);
  ushort4 o;
  o.x = f2bf(v.x); o.y = f2bf(v.y); o.z = f2bf(v.z); o.w = f2bf(v.w);
  *reinterpret_cast<ushort4*>(dst + i) = o;
}

// --------------------------------------------- cast + transpose W -> [N][K]
__global__ void cast_wt_kernel(const float* __restrict__ w0, const float* __restrict__ w1,
                               const float* __restrict__ w2, const float* __restrict__ w3,
                               unsigned short* __restrict__ t0, unsigned short* __restrict__ t1,
                               unsigned short* __restrict__ t2, unsigned short* __restrict__ t3) {
  const float* src; unsigned short* dst;
  switch (blockIdx.z) {
    case 0:  src = w0; dst = t0; break;
    case 1:  src = w1; dst = t1; break;
    case 2:  src = w2; dst = t2; break;
    default: src = w3; dst = t3; break;
  }
  __shared__ float tile[64][65];
  const int n0 = blockIdx.x * 64, k0 = blockIdx.y * 64;
  const int t = threadIdx.x;
#pragma unroll
  for (int i = 0; i < 4; ++i) {               // load 64x64 fp32 tile, rows = k
    const int q = t + i * 256, r = q >> 4, c4 = q & 15;
    const float4 v = *reinterpret_cast<const float4*>(src + (k0 + r) * 1024 + n0 + c4 * 4);
    tile[r][c4 * 4 + 0] = v.x; tile[r][c4 * 4 + 1] = v.y;
    tile[r][c4 * 4 + 2] = v.z; tile[r][c4 * 4 + 3] = v.w;
  }
  __syncthreads();
#pragma unroll
  for (int i = 0; i < 4; ++i) {               // write Wt[n][k] bf16
    const int q = t + i * 256, n = q >> 4, c4 = q & 15;
    ushort4 o;
    o.x = f2bf(tile[c4 * 4 + 0][n]); o.y = f2bf(tile[c4 * 4 + 1][n]);
    o.z = f2bf(tile[c4 * 4 + 2][n]); o.w = f2bf(tile[c4 * 4 + 3][n]);
    *reinterpret_cast<ushort4*>(dst + (n0 + n) * 1024 + k0 + c4 * 4) = o;
  }
}

// ------------------------------------------------------------------- GEMM
// C[M=4096][N] = A[M][1024] @ Bt^T (+ bias). Bt is [N][K]. 128x128 tile, BK=64,
// 4 waves of 64x64. MODE 0: fused QKV (Q pre-scaled by 0.125*log2e), bf16 out
// scattered to [b,h,s,d]. MODE 1: single weight, fp32 out.
template <int MODE>
__global__ __launch_bounds__(256, 2) void gemm128(
    const unsigned short* __restrict__ A,
    const unsigned short* __restrict__ BtQ, const unsigned short* __restrict__ BtK,
    const unsigned short* __restrict__ BtV,
    const float* __restrict__ biasQ, const float* __restrict__ biasK,
    const float* __restrict__ biasV,
    unsigned short* __restrict__ OQ, unsigned short* __restrict__ OK_,
    unsigned short* __restrict__ OV, float* __restrict__ OF) {
  __shared__ unsigned short As[128 * 64];
  __shared__ unsigned short Bs[128 * 64];

  const int mt = blockIdx.x, nt = blockIdx.y;
  const unsigned short* Bt; const float* bias;
  unsigned short* Obf = nullptr;
  int nloc0;
  float scl = 1.0f;
  if (MODE == 0) {
    const int which = nt >> 3;
    nloc0 = (nt & 7) * 128;
    Bt   = (which == 0) ? BtQ   : (which == 1) ? BtK   : BtV;
    bias = (which == 0) ? biasQ : (which == 1) ? biasK : biasV;
    Obf  = (which == 0) ? OQ    : (which == 1) ? OK_   : OV;
    if (which == 0) scl = 0.18033688f;        // 0.125 * log2(e)
  } else {
    nloc0 = nt * 128;
    Bt = BtQ; bias = biasQ;
  }
  const int m0 = mt * 128;
  const int t = threadIdx.x;
  const int w = t >> 6, l = t & 63;
  const int wm = (w >> 1) * 64, wn = (w & 1) * 64;
  const int lr = l & 15, lg = l >> 4;

  f32x4 acc[4][4];
#pragma unroll
  for (int i = 0; i < 4; ++i)
#pragma unroll
    for (int j = 0; j < 4; ++j) acc[i][j] = f32x4{0.f, 0.f, 0.f, 0.f};

  for (int k0 = 0; k0 < 1024; k0 += 64) {
#pragma unroll
    for (int i = 0; i < 4; ++i) {             // stage A tile: [128 m][64 k]
      const int off = t * 16 + i * 4096;
      const int r = off >> 7, cb = off & 127;
      GLDS16(A + (m0 + r) * 1024 + k0 + (cb >> 1), ((char*)As) + off);
    }
#pragma unroll
    for (int i = 0; i < 4; ++i) {             // stage B tile: [128 n][64 k]
      const int off = t * 16 + i * 4096;
      const int r = off >> 7, cb = off & 127;
      GLDS16(Bt + (nloc0 + r) * 1024 + k0 + (cb >> 1), ((char*)Bs) + off);
    }
    __syncthreads();
#pragma unroll
    for (int kk = 0; kk < 2; ++kk) {
      bf16x8 af[4], bfr[4];
#pragma unroll
      for (int mi = 0; mi < 4; ++mi)
        af[mi] = ld_bf8(As + (wm + mi * 16 + lr) * 64 + kk * 32 + lg * 8);
#pragma unroll
      for (int ni = 0; ni < 4; ++ni)
        bfr[ni] = ld_bf8(Bs + (wn + ni * 16 + lr) * 64 + kk * 32 + lg * 8);
#pragma unroll
      for (int mi = 0; mi < 4; ++mi)
#pragma unroll
        for (int ni = 0; ni < 4; ++ni)
          acc[mi][ni] = __builtin_amdgcn_mfma_f32_16x16x32_bf16(af[mi], bfr[ni], acc[mi][ni], 0, 0, 0);
    }
    __syncthreads();
  }

#pragma unroll
  for (int ni = 0; ni < 4; ++ni) {
    const int n = nloc0 + wn + ni * 16 + lr;  // column within this weight
    const float bv = bias[n];
#pragma unroll
    for (int mi = 0; mi < 4; ++mi) {
#pragma unroll
      for (int r = 0; r < 4; ++r) {
        const int m = m0 + wm + mi * 16 + 4 * lg + r;
        const float v = (acc[mi][ni][r] + bv) * scl;
        if (MODE == 0) {
          const int b = m >> 11, s = m & 2047;
          const int h = n >> 6,  d = n & 63;
          Obf[(((b * 16 + h) * 2048) + s) * 64 + d] = f2bf(v);
        } else {
          OF[m * 1024 + n] = v;
        }
      }
    }
  }
}

// ------------------------------------------- V [b,h,s,d] -> Vt [b,h,d,s]
__global__ void transpose_v_kernel(const unsigned short* __restrict__ Vh,
                                   unsigned short* __restrict__ Vt) {
  const int bh = blockIdx.y;
  const int s0 = blockIdx.x * 64;
  __shared__ unsigned short tile[64][72];
  const int t = threadIdx.x;
#pragma unroll
  for (int i = 0; i < 4; ++i) {
    const int q = t + i * 256, r = q >> 4, c4 = q & 15;
    const ushort4 v = *reinterpret_cast<const ushort4*>(Vh + ((size_t)bh * 2048 + s0 + r) * 64 + c4 * 4);
    tile[r][c4 * 4 + 0] = v.x; tile[r][c4 * 4 + 1] = v.y;
    tile[r][c4 * 4 + 2] = v.z; tile[r][c4 * 4 + 3] = v.w;
  }
  __syncthreads();
#pragma unroll
  for (int i = 0; i < 4; ++i) {
    const int q = t + i * 256, d = q >> 4, c4 = q & 15;
    ushort4 o;
    o.x = tile[c4 * 4 + 0][d]; o.y = tile[c4 * 4 + 1][d];
    o.z = tile[c4 * 4 + 2][d]; o.w = tile[c4 * 4 + 3][d];
    *reinterpret_cast<ushort4*>(Vt + ((size_t)bh * 64 + d) * 2048 + s0 + c4 * 4) = o;
  }
}

// ------------------------------------------------------- flash attention v4
// Swapped QK^T (S^T: q = lane&15, kv in-lane), in-register softmax with
// defer-max (no cross-lane reduce on common path; per-lane partial l reduced
// at epilogue), both frags' chains interleaved. LPT-balanced grid pairing.
__global__ __launch_bounds__(256, 2) void attn_kernel(
    const unsigned short* __restrict__ Qh, const unsigned short* __restrict__ Kh,
    const unsigned short* __restrict__ Vt, unsigned short* __restrict__ Ob) {
  const int g = blockIdx.x;
  const int qt = (g < 256) ? (15 - (g >> 5)) : (7 - ((g - 256) >> 5));
  const int bh = g & 31;
  const int b = bh >> 4, h = bh & 15;
  const int t = threadIdx.x, w = t >> 6, l = t & 63;
  const int lr = l & 15, lg = l >> 4;
  const int sl0 = lr + 32 * (lg & 1);        // pack-shuffle source lanes
  const int sl1 = sl0 + 16;
  const bool hi2 = (l & 32) != 0;

  __shared__ unsigned short Kb[2][4096];     // [64 kv][64 d], swizzled
  __shared__ unsigned short Vb[2][4096];     // [64 d][64 kv], swizzled

  const unsigned short* Kbase = Kh + (size_t)bh * (2048 * 64);
  const unsigned short* Vbase = Vt + (size_t)bh * (64 * 2048);

  const int qb0 = qt * 128 + w * 16;
  const int qb1 = qb0 + 64;

  const unsigned short* Qp0 = Qh + ((size_t)bh * 2048 + qb0 + lr) * 64;
  const unsigned short* Qp1 = Qh + ((size_t)bh * 2048 + qb1 + lr) * 64;
  bf16x8 qf[2][2];
  qf[0][0] = ld_bf8(Qp0 + lg * 8);
  qf[0][1] = ld_bf8(Qp0 + 32 + lg * 8);
  qf[1][0] = ld_bf8(Qp1 + lg * 8);
  qf[1][1] = ld_bf8(Qp1 + 32 + lg * 8);

  f32x4 oacc[2][4];                          // O^T: lane q=qb+lr, d=df*16+4lg+r
#pragma unroll
  for (int f = 0; f < 2; ++f)
#pragma unroll
    for (int i = 0; i < 4; ++i) oacc[f][i] = f32x4{0.f, 0.f, 0.f, 0.f};
  float mrun[2] = {-3e38f, -3e38f};
  float lpart[2] = {0.f, 0.f};               // per-lane partial denominators

  auto stage = [&](int kv0, int bi) {
#pragma unroll
    for (int p = 0; p < 2; ++p) {
      const int o = t * 16 + p * 4096;       // linear byte offset in 8KB tile
      const int row = o >> 7;
      const int scb = (o & 127) ^ ((row & 7) << 4);   // pre-swizzled src col
      GLDS16(Kbase + (size_t)(kv0 + row) * 64 + (scb >> 1), ((char*)Kb[bi]) + o);
      GLDS16(Vbase + (size_t)row * 2048 + kv0 + (scb >> 1), ((char*)Vb[bi]) + o);
    }
  };

  auto lmax16 = [](const f32x4* s) {         // balanced tree (max3-fusible)
    const float a = fmaxf(fmaxf(s[0][0], s[0][1]), fmaxf(s[0][2], s[0][3]));
    const float b2 = fmaxf(fmaxf(s[1][0], s[1][1]), fmaxf(s[1][2], s[1][3]));
    const float c = fmaxf(fmaxf(s[2][0], s[2][1]), fmaxf(s[2][2], s[2][3]));
    const float d = fmaxf(fmaxf(s[3][0], s[3][1]), fmaxf(s[3][2], s[3][3]));
    return fmaxf(fmaxf(a, b2), fmaxf(c, d));
  };

  auto mask = [&](f32x4* s, int qb, int kv0) {
#pragma unroll
    for (int nf = 0; nf < 4; ++nf) {
      const int kv = kv0 + nf * 16 + 4 * lg;
#pragma unroll
      for (int r = 0; r < 4; ++r)
        if (kv + r > qb + lr) s[nf][r] = -3e38f;
    }
  };

  // pack P^T (S^T frag, already exp'd) into PV B-operand fragments
  auto pack = [&](const f32x4* s, bf16x8* pa) {
    unsigned wpk[4][2];
#pragma unroll
    for (int nf = 0; nf < 4; ++nf) {
      asm("v_cvt_pk_bf16_f32 %0, %1, %2" : "=v"(wpk[nf][0]) : "v"(s[nf][0]), "v"(s[nf][1]));
      asm("v_cvt_pk_bf16_f32 %0, %1, %2" : "=v"(wpk[nf][1]) : "v"(s[nf][2]), "v"(s[nf][3]));
    }
#pragma unroll
    for (int kf = 0; kf < 2; ++kf) {
      const unsigned a0w = __shfl(wpk[2 * kf][0], sl0), b0w = __shfl(wpk[2 * kf + 1][0], sl0);
      const unsigned a1w = __shfl(wpk[2 * kf][1], sl0), b1w = __shfl(wpk[2 * kf + 1][1], sl0);
      const unsigned a2w = __shfl(wpk[2 * kf][0], sl1), b2w = __shfl(wpk[2 * kf + 1][0], sl1);
      const unsigned a3w = __shfl(wpk[2 * kf][1], sl1), b3w = __shfl(wpk[2 * kf + 1][1], sl1);
      u32x4 uu;
      uu[0] = hi2 ? b0w : a0w;
      uu[1] = hi2 ? b1w : a1w;
      uu[2] = hi2 ? b2w : a2w;
      uu[3] = hi2 ? b3w : a3w;
      pa[kf] = __builtin_bit_cast(bf16x8, uu);
    }
  };

  const int nt = 2 * qt + 2;
  stage(0, 0);
  __syncthreads();

  for (int ti = 0; ti < nt; ++ti) {
    const int cur = ti & 1;
    const int kv0 = ti * 64;
    if (ti + 1 < nt) stage((ti + 1) * 64, cur ^ 1);

    const bool a0 = (kv0 <= qb0 + 15);       // frag1 always active

    // ---- QK^T (swapped: S^T = K . Q^T), K loads shared across frags
    f32x4 s0[4], s1[4];
#pragma unroll
    for (int i = 0; i < 4; ++i) { s0[i] = f32x4{0.f,0.f,0.f,0.f}; s1[i] = f32x4{0.f,0.f,0.f,0.f}; }
    __builtin_amdgcn_s_setprio(1);
#pragma unroll
    for (int kf = 0; kf < 2; ++kf) {
#pragma unroll
      for (int nf = 0; nf < 4; ++nf) {
        const int row = nf * 16 + lr;
        const int col = (kf * 32 + lg * 8) ^ ((row & 7) << 3);
        const bf16x8 kb = ld_bf8(&Kb[cur][row * 64 + col]);
        if (a0) s0[nf] = __builtin_amdgcn_mfma_f32_16x16x32_bf16(kb, qf[0][kf], s0[nf], 0, 0, 0);
        s1[nf] = __builtin_amdgcn_mfma_f32_16x16x32_bf16(kb, qf[1][kf], s1[nf], 0, 0, 0);
      }
    }
    __builtin_amdgcn_s_setprio(0);

    // ---- softmax, both frags interleaved; no cross-lane ops on common path
    if (a0 && kv0 + 63 > qb0) mask(s0, qb0, kv0);
    if (kv0 + 63 > qb1) mask(s1, qb1, kv0);
    const float mx0 = a0 ? lmax16(s0) : -3e38f;
    const float mx1 = lmax16(s1);
    if (!__all((mx0 <= mrun[0] + 8.f) && (mx1 <= mrun[1] + 8.f))) {
      float m0 = fmaxf(mx0, __shfl_xor(mx0, 16));
      float m1 = fmaxf(mx1, __shfl_xor(mx1, 16));
      m0 = fmaxf(m0, __shfl_xor(m0, 32));
      m1 = fmaxf(m1, __shfl_xor(m1, 32));
      const float n0 = fmaxf(mrun[0], m0), n1 = fmaxf(mrun[1], m1);
      const float c0 = __builtin_amdgcn_exp2f(mrun[0] - n0);
      const float c1 = __builtin_amdgcn_exp2f(mrun[1] - n1);
      mrun[0] = n0; mrun[1] = n1;
      lpart[0] *= c0; lpart[1] *= c1;
#pragma unroll
      for (int df = 0; df < 4; ++df)
#pragma unroll
        for (int r = 0; r < 4; ++r) { oacc[0][df][r] *= c0; oacc[1][df][r] *= c1; }
    }
    float rs0 = 0.f, rs1 = 0.f;
    if (a0) {
#pragma unroll
      for (int nf = 0; nf < 4; ++nf)
#pragma unroll
        for (int r = 0; r < 4; ++r) {
          const float p = __builtin_amdgcn_exp2f(s0[nf][r] - mrun[0]);
          s0[nf][r] = p; rs0 += p;
        }
    }
#pragma unroll
    for (int nf = 0; nf < 4; ++nf)
#pragma unroll
      for (int r = 0; r < 4; ++r) {
        const float p = __builtin_amdgcn_exp2f(s1[nf][r] - mrun[1]);
        s1[nf][r] = p; rs1 += p;
      }
    lpart[0] += rs0; lpart[1] += rs1;

    bf16x8 pa0[2], pa1[2];
    if (a0) pack(s0, pa0);
    pack(s1, pa1);

    // ---- PV: O^T += V^T . P^T, V loads shared across frags
    __builtin_amdgcn_s_setprio(1);
#pragma unroll
    for (int kf = 0; kf < 2; ++kf) {
#pragma unroll
      for (int df = 0; df < 4; ++df) {
        const int vrow = df * 16 + lr;
        const int vcol = (kf * 32 + lg * 8) ^ ((vrow & 7) << 3);
        const bf16x8 vb = ld_bf8(&Vb[cur][vrow * 64 + vcol]);
        if (a0) oacc[0][df] = __builtin_amdgcn_mfma_f32_16x16x32_bf16(vb, pa0[kf], oacc[0][df], 0, 0, 0);
        oacc[1][df] = __builtin_amdgcn_mfma_f32_16x16x32_bf16(vb, pa1[kf], oacc[1][df], 0, 0, 0);
      }
    }
    __builtin_amdgcn_s_setprio(0);
    __syncthreads();                         // drains prefetch + guards buffers
  }

#pragma unroll
  for (int fi = 0; fi < 2; ++fi) {
    const int qb = fi ? qb1 : qb0;
    float ls = lpart[fi];
    ls += __shfl_xor(ls, 16);
    ls += __shfl_xor(ls, 32);
    const float inv = 1.f / ls;
    const int q = qb + lr;
#pragma unroll
    for (int df = 0; df < 4; ++df) {
      ushort4 o4;
      o4.x = bfc(oacc[fi][df][0] * inv);
      o4.y = bfc(oacc[fi][df][1] * inv);
      o4.z = bfc(oacc[fi][df][2] * inv);
      o4.w = bfc(oacc[fi][df][3] * inv);
      *reinterpret_cast<ushort4*>(
          &Ob[((size_t)(b * 2048 + q)) * 1024 + h * 64 + df * 16 + 4 * lg]) = o4;
    }
  }
}

// ------------------------------------------------------------------ launch
extern "C" void kernel_launch(void* const* d_in, const int* in_sizes, int n_in,
                              void* d_out, int out_size, void* d_ws, size_t ws_size,
                              hipStream_t stream) {
  const float* x  = (const float*)d_in[0];
  const float* Wq = (const float*)d_in[1];
  const float* bq = (const float*)d_in[2];
  const float* Wk = (const float*)d_in[3];
  const float* bk = (const float*)d_in[4];
  const float* Wv = (const float*)d_in[5];
  const float* bv = (const float*)d_in[6];
  const float* Wo = (const float*)d_in[7];
  const float* bo = (const float*)d_in[8];
  float* out = (float*)d_out;

  unsigned short* xb  = (unsigned short*)d_ws;          // 4096*1024
  unsigned short* wqt = xb  + 4096 * 1024;              // 1024*1024 each
  unsigned short* wkt = wqt + 1024 * 1024;
  unsigned short* wvt = wkt + 1024 * 1024;
  unsigned short* wot = wvt + 1024 * 1024;
  unsigned short* Qh  = wot + 1024 * 1024;              // [b,h,s,d]
  unsigned short* Kh  = Qh  + 4096 * 1024;
  unsigned short* Vh  = Kh  + 4096 * 1024;
  unsigned short* Vt  = Vh  + 4096 * 1024;              // [b,h,d,s]
  unsigned short* Ob  = Vt  + 4096 * 1024;              // [4096][1024]

  cast_x_kernel<<<4096, 256, 0, stream>>>(x, xb);
  cast_wt_kernel<<<dim3(16, 16, 4), 256, 0, stream>>>(Wq, Wk, Wv, Wo, wqt, wkt, wvt, wot);
  gemm128<0><<<dim3(32, 24), 256, 0, stream>>>(xb, wqt, wkt, wvt, bq, bk, bv,
                                               Qh, Kh, Vh, nullptr);
  transpose_v_kernel<<<dim3(32, 32), 256, 0, stream>>>(Vh, Vt);
  attn_kernel<<<512, 256, 0, stream>>>(Qh, Kh, Vt, Ob);
  gemm128<1><<<dim3(32, 8), 256, 0, stream>>>(Ob, wot, nullptr, nullptr, bo, nullptr, nullptr,
                                              nullptr, nullptr, nullptr, out);
}

// Round 5
// 121.234 us; speedup vs baseline: 2.4978x; 1.2626x over previous
//
#include <hip/hip_runtime.h>

// Masked causal MHA: B=2, S=2048, E=1024, H=16, D=64.
// ws layout (bf16/ushort): xb[4096*1024] | wqt|wkt|wvt|wot[1024*1024 each, [N][K]]
//   | Qh|Kh|Vh [b,h,s,d] | Vt [b,h,d,s] | Ob [4096][1024].  Total ~56 MB.

using f32x4  = __attribute__((ext_vector_type(4))) float;
using bf16x8 = __attribute__((ext_vector_type(8))) __bf16;
using u16x8  = __attribute__((ext_vector_type(8))) unsigned short;
using u32x4  = __attribute__((ext_vector_type(4))) unsigned int;

__device__ __forceinline__ unsigned short f2bf(float f) {
  unsigned u = __float_as_uint(f);
  u += 0x7fff + ((u >> 16) & 1u);            // round-to-nearest-even
  return (unsigned short)(u >> 16);
}

__device__ __forceinline__ unsigned short bfc(float f) {   // HW cvt
  __bf16 h = (__bf16)f;
  return __builtin_bit_cast(unsigned short, h);
}

__device__ __forceinline__ bf16x8 ld_bf8(const unsigned short* p) {
  return __builtin_bit_cast(bf16x8, *reinterpret_cast<const u16x8*>(p));
}

#define GLDS16(gp, lp)                                                        \
  __builtin_amdgcn_global_load_lds(                                           \
      (__attribute__((address_space(1))) void*)(gp),                          \
      (__attribute__((address_space(3))) void*)(lp), 16, 0, 0)

// ---------------------------------------------------------------- cast x
__global__ void cast_x_kernel(const float* __restrict__ src,
                              unsigned short* __restrict__ dst) {
  const int i = (blockIdx.x * 256 + threadIdx.x) * 4;
  const float4 v = *reinterpret_cast<const float4*>(src + i);
  ushort4 o;
  o.x = f2bf(v.x); o.y = f2bf(v.y); o.z = f2bf(v.z); o.w = f2bf(v.w);
  *reinterpret_cast<ushort4*>(dst + i) = o;
}

// --------------------------------------------- cast + transpose W -> [N][K]
__global__ void cast_wt_kernel(const float* __restrict__ w0, const float* __restrict__ w1,
                               const float* __restrict__ w2, const float* __restrict__ w3,
                               unsigned short* __restrict__ t0, unsigned short* __restrict__ t1,
                               unsigned short* __restrict__ t2, unsigned short* __restrict__ t3) {
  const float* src; unsigned short* dst;
  switch (blockIdx.z) {
    case 0:  src = w0; dst = t0; break;
    case 1:  src = w1; dst = t1; break;
    case 2:  src = w2; dst = t2; break;
    default: src = w3; dst = t3; break;
  }
  __shared__ float tile[64][65];
  const int n0 = blockIdx.x * 64, k0 = blockIdx.y * 64;
  const int t = threadIdx.x;
#pragma unroll
  for (int i = 0; i < 4; ++i) {               // load 64x64 fp32 tile, rows = k
    const int q = t + i * 256, r = q >> 4, c4 = q & 15;
    const float4 v = *reinterpret_cast<const float4*>(src + (k0 + r) * 1024 + n0 + c4 * 4);
    tile[r][c4 * 4 + 0] = v.x; tile[r][c4 * 4 + 1] = v.y;
    tile[r][c4 * 4 + 2] = v.z; tile[r][c4 * 4 + 3] = v.w;
  }
  __syncthreads();
#pragma unroll
  for (int i = 0; i < 4; ++i) {               // write Wt[n][k] bf16
    const int q = t + i * 256, n = q >> 4, c4 = q & 15;
    ushort4 o;
    o.x = f2bf(tile[c4 * 4 + 0][n]); o.y = f2bf(tile[c4 * 4 + 1][n]);
    o.z = f2bf(tile[c4 * 4 + 2][n]); o.w = f2bf(tile[c4 * 4 + 3][n]);
    *reinterpret_cast<ushort4*>(dst + (n0 + n) * 1024 + k0 + c4 * 4) = o;
  }
}

// ------------------------------------------------------------------- GEMM
// C[M=4096][N] = A[M][1024] @ Bt^T (+ bias). Bt is [N][K]. 128x128 tile, BK=64,
// 4 waves of 64x64. MODE 0: fused QKV (Q pre-scaled by 0.125*log2e), bf16 out
// scattered to [b,h,s,d]. MODE 1: single weight, fp32 out.
template <int MODE>
__global__ __launch_bounds__(256, 2) void gemm128(
    const unsigned short* __restrict__ A,
    const unsigned short* __restrict__ BtQ, const unsigned short* __restrict__ BtK,
    const unsigned short* __restrict__ BtV,
    const float* __restrict__ biasQ, const float* __restrict__ biasK,
    const float* __restrict__ biasV,
    unsigned short* __restrict__ OQ, unsigned short* __restrict__ OK_,
    unsigned short* __restrict__ OV, float* __restrict__ OF) {
  __shared__ unsigned short As[128 * 64];
  __shared__ unsigned short Bs[128 * 64];

  const int mt = blockIdx.x, nt = blockIdx.y;
  const unsigned short* Bt; const float* bias;
  unsigned short* Obf = nullptr;
  int nloc0;
  float scl = 1.0f;
  if (MODE == 0) {
    const int which = nt >> 3;
    nloc0 = (nt & 7) * 128;
    Bt   = (which == 0) ? BtQ   : (which == 1) ? BtK   : BtV;
    bias = (which == 0) ? biasQ : (which == 1) ? biasK : biasV;
    Obf  = (which == 0) ? OQ    : (which == 1) ? OK_   : OV;
    if (which == 0) scl = 0.18033688f;        // 0.125 * log2(e)
  } else {
    nloc0 = nt * 128;
    Bt = BtQ; bias = biasQ;
  }
  const int m0 = mt * 128;
  const int t = threadIdx.x;
  const int w = t >> 6, l = t & 63;
  const int wm = (w >> 1) * 64, wn = (w & 1) * 64;
  const int lr = l & 15, lg = l >> 4;

  f32x4 acc[4][4];
#pragma unroll
  for (int i = 0; i < 4; ++i)
#pragma unroll
    for (int j = 0; j < 4; ++j) acc[i][j] = f32x4{0.f, 0.f, 0.f, 0.f};

  for (int k0 = 0; k0 < 1024; k0 += 64) {
#pragma unroll
    for (int i = 0; i < 4; ++i) {             // stage A tile: [128 m][64 k]
      const int off = t * 16 + i * 4096;
      const int r = off >> 7, cb = off & 127;
      GLDS16(A + (m0 + r) * 1024 + k0 + (cb >> 1), ((char*)As) + off);
    }
#pragma unroll
    for (int i = 0; i < 4; ++i) {             // stage B tile: [128 n][64 k]
      const int off = t * 16 + i * 4096;
      const int r = off >> 7, cb = off & 127;
      GLDS16(Bt + (nloc0 + r) * 1024 + k0 + (cb >> 1), ((char*)Bs) + off);
    }
    __syncthreads();
#pragma unroll
    for (int kk = 0; kk < 2; ++kk) {
      bf16x8 af[4], bfr[4];
#pragma unroll
      for (int mi = 0; mi < 4; ++mi)
        af[mi] = ld_bf8(As + (wm + mi * 16 + lr) * 64 + kk * 32 + lg * 8);
#pragma unroll
      for (int ni = 0; ni < 4; ++ni)
        bfr[ni] = ld_bf8(Bs + (wn + ni * 16 + lr) * 64 + kk * 32 + lg * 8);
#pragma unroll
      for (int mi = 0; mi < 4; ++mi)
#pragma unroll
        for (int ni = 0; ni < 4; ++ni)
          acc[mi][ni] = __builtin_amdgcn_mfma_f32_16x16x32_bf16(af[mi], bfr[ni], acc[mi][ni], 0, 0, 0);
    }
    __syncthreads();
  }

#pragma unroll
  for (int ni = 0; ni < 4; ++ni) {
    const int n = nloc0 + wn + ni * 16 + lr;  // column within this weight
    const float bv = bias[n];
#pragma unroll
    for (int mi = 0; mi < 4; ++mi) {
#pragma unroll
      for (int r = 0; r < 4; ++r) {
        const int m = m0 + wm + mi * 16 + 4 * lg + r;
        const float v = (acc[mi][ni][r] + bv) * scl;
        if (MODE == 0) {
          const int b = m >> 11, s = m & 2047;
          const int h = n >> 6,  d = n & 63;
          Obf[(((b * 16 + h) * 2048) + s) * 64 + d] = f2bf(v);
        } else {
          OF[m * 1024 + n] = v;
        }
      }
    }
  }
}

// ------------------------------------------- V [b,h,s,d] -> Vt [b,h,d,s]
__global__ void transpose_v_kernel(const unsigned short* __restrict__ Vh,
                                   unsigned short* __restrict__ Vt) {
  const int bh = blockIdx.y;
  const int s0 = blockIdx.x * 64;
  __shared__ unsigned short tile[64][72];
  const int t = threadIdx.x;
#pragma unroll
  for (int i = 0; i < 4; ++i) {
    const int q = t + i * 256, r = q >> 4, c4 = q & 15;
    const ushort4 v = *reinterpret_cast<const ushort4*>(Vh + ((size_t)bh * 2048 + s0 + r) * 64 + c4 * 4);
    tile[r][c4 * 4 + 0] = v.x; tile[r][c4 * 4 + 1] = v.y;
    tile[r][c4 * 4 + 2] = v.z; tile[r][c4 * 4 + 3] = v.w;
  }
  __syncthreads();
#pragma unroll
  for (int i = 0; i < 4; ++i) {
    const int q = t + i * 256, d = q >> 4, c4 = q & 15;
    ushort4 o;
    o.x = tile[c4 * 4 + 0][d]; o.y = tile[c4 * 4 + 1][d];
    o.z = tile[c4 * 4 + 2][d]; o.w = tile[c4 * 4 + 3][d];
    *reinterpret_cast<ushort4*>(Vt + ((size_t)bh * 64 + d) * 2048 + s0 + c4 * 4) = o;
  }
}

// ------------------------------------------------------- flash attention v5
// 64-row q-blocks (1024 blocks, 4 blocks/CU, 16 waves/CU) for latency hiding.
// Swapped QK^T (S^T: q = lane&15, kv in-lane), in-register softmax, defer-max,
// per-lane partial l (reduced at epilogue), LPT (qt-descending) grid order.
__global__ __launch_bounds__(256, 4) void attn_kernel(
    const unsigned short* __restrict__ Qh, const unsigned short* __restrict__ Kh,
    const unsigned short* __restrict__ Vt, unsigned short* __restrict__ Ob) {
  const int g = blockIdx.x;
  const int qt = 31 - (g >> 5);              // LPT: longest first
  const int bh = g & 31;
  const int b = bh >> 4, h = bh & 15;
  const int t = threadIdx.x, w = t >> 6, l = t & 63;
  const int lr = l & 15, lg = l >> 4;
  const int sl0 = lr + 32 * (lg & 1);        // pack-shuffle source lanes
  const int sl1 = sl0 + 16;
  const bool hi2 = (l & 32) != 0;

  __shared__ unsigned short Kb[2][4096];     // [64 kv][64 d], swizzled
  __shared__ unsigned short Vb[2][4096];     // [64 d][64 kv], swizzled

  const unsigned short* Kbase = Kh + (size_t)bh * (2048 * 64);
  const unsigned short* Vbase = Vt + (size_t)bh * (64 * 2048);

  const int qb = qt * 64 + w * 16;           // this wave's 16 q rows
  const unsigned short* Qp = Qh + ((size_t)bh * 2048 + qb + lr) * 64;
  bf16x8 qf[2];
  qf[0] = ld_bf8(Qp + lg * 8);
  qf[1] = ld_bf8(Qp + 32 + lg * 8);

  f32x4 oacc[4];                             // O^T: lane q=qb+lr, d=df*16+4lg+r
#pragma unroll
  for (int i = 0; i < 4; ++i) oacc[i] = f32x4{0.f, 0.f, 0.f, 0.f};
  float mrun = -3e38f;
  float lpart = 0.f;                         // per-lane partial denominator

  auto stage = [&](int kv0, int bi) {
#pragma unroll
    for (int p = 0; p < 2; ++p) {
      const int o = t * 16 + p * 4096;       // linear byte offset in 8KB tile
      const int row = o >> 7;
      const int scb = (o & 127) ^ ((row & 7) << 4);   // pre-swizzled src col
      GLDS16(Kbase + (size_t)(kv0 + row) * 64 + (scb >> 1), ((char*)Kb[bi]) + o);
      GLDS16(Vbase + (size_t)row * 2048 + kv0 + (scb >> 1), ((char*)Vb[bi]) + o);
    }
  };

  const int nt = qt + 1;
  stage(0, 0);
  __syncthreads();

  for (int ti = 0; ti < nt; ++ti) {
    const int cur = ti & 1;
    const int kv0 = ti * 64;
    if (ti + 1 < nt) stage((ti + 1) * 64, cur ^ 1);

    // ---- QK^T (swapped: S^T = K . Q^T)
    f32x4 s[4];
#pragma unroll
    for (int i = 0; i < 4; ++i) s[i] = f32x4{0.f, 0.f, 0.f, 0.f};
    __builtin_amdgcn_s_setprio(1);
#pragma unroll
    for (int kf = 0; kf < 2; ++kf) {
#pragma unroll
      for (int nf = 0; nf < 4; ++nf) {
        const int row = nf * 16 + lr;
        const int col = (kf * 32 + lg * 8) ^ ((row & 7) << 3);
        const bf16x8 kb = ld_bf8(&Kb[cur][row * 64 + col]);
        s[nf] = __builtin_amdgcn_mfma_f32_16x16x32_bf16(kb, qf[kf], s[nf], 0, 0, 0);
      }
    }
    __builtin_amdgcn_s_setprio(0);

    // ---- softmax (no cross-lane ops on common path)
    if (ti == qt) {                          // diagonal tile: causal mask
#pragma unroll
      for (int nf = 0; nf < 4; ++nf) {
        const int kv = kv0 + nf * 16 + 4 * lg;
#pragma unroll
        for (int r = 0; r < 4; ++r)
          if (kv + r > qb + lr) s[nf][r] = -3e38f;
      }
    }
    float m01 = -3e38f, m23 = -3e38f;        // balanced per-lane max tree
#pragma unroll
    for (int r = 0; r < 4; ++r) {
      m01 = fmaxf(m01, fmaxf(s[0][r], s[1][r]));
      m23 = fmaxf(m23, fmaxf(s[2][r], s[3][r]));
    }
    const float mx = fmaxf(m01, m23);
    if (!__all(mx <= mrun + 8.f)) {          // defer-max (T13)
      float m0 = fmaxf(mx, __shfl_xor(mx, 16));
      m0 = fmaxf(m0, __shfl_xor(m0, 32));
      const float n0 = fmaxf(mrun, m0);
      const float c0 = __builtin_amdgcn_exp2f(mrun - n0);
      mrun = n0;
      lpart *= c0;
#pragma unroll
      for (int df = 0; df < 4; ++df)
#pragma unroll
        for (int r = 0; r < 4; ++r) oacc[df][r] *= c0;
    }
    float rs[4] = {0.f, 0.f, 0.f, 0.f};      // 4 independent partial sums
#pragma unroll
    for (int nf = 0; nf < 4; ++nf)
#pragma unroll
      for (int r = 0; r < 4; ++r) {
        const float p = __builtin_amdgcn_exp2f(s[nf][r] - mrun);
        s[nf][r] = p;
        rs[nf] += p;
      }
    lpart += (rs[0] + rs[1]) + (rs[2] + rs[3]);

    // ---- pack P^T into PV B-operand fragments (in registers)
    unsigned wpk[4][2];
#pragma unroll
    for (int nf = 0; nf < 4; ++nf) {
      asm("v_cvt_pk_bf16_f32 %0, %1, %2" : "=v"(wpk[nf][0]) : "v"(s[nf][0]), "v"(s[nf][1]));
      asm("v_cvt_pk_bf16_f32 %0, %1, %2" : "=v"(wpk[nf][1]) : "v"(s[nf][2]), "v"(s[nf][3]));
    }
    bf16x8 pa[2];
#pragma unroll
    for (int kf = 0; kf < 2; ++kf) {
      const unsigned a0w = __shfl(wpk[2 * kf][0], sl0), b0w = __shfl(wpk[2 * kf + 1][0], sl0);
      const unsigned a1w = __shfl(wpk[2 * kf][1], sl0), b1w = __shfl(wpk[2 * kf + 1][1], sl0);
      const unsigned a2w = __shfl(wpk[2 * kf][0], sl1), b2w = __shfl(wpk[2 * kf + 1][0], sl1);
      const unsigned a3w = __shfl(wpk[2 * kf][1], sl1), b3w = __shfl(wpk[2 * kf + 1][1], sl1);
      u32x4 uu;
      uu[0] = hi2 ? b0w : a0w;
      uu[1] = hi2 ? b1w : a1w;
      uu[2] = hi2 ? b2w : a2w;
      uu[3] = hi2 ? b3w : a3w;
      pa[kf] = __builtin_bit_cast(bf16x8, uu);
    }

    // ---- PV: O^T += V^T . P^T
    __builtin_amdgcn_s_setprio(1);
#pragma unroll
    for (int kf = 0; kf < 2; ++kf) {
#pragma unroll
      for (int df = 0; df < 4; ++df) {
        const int vrow = df * 16 + lr;
        const int vcol = (kf * 32 + lg * 8) ^ ((vrow & 7) << 3);
        const bf16x8 vb = ld_bf8(&Vb[cur][vrow * 64 + vcol]);
        oacc[df] = __builtin_amdgcn_mfma_f32_16x16x32_bf16(vb, pa[kf], oacc[df], 0, 0, 0);
      }
    }
    __builtin_amdgcn_s_setprio(0);
    __syncthreads();                         // drains prefetch + guards buffers
  }

  float ls = lpart;
  ls += __shfl_xor(ls, 16);
  ls += __shfl_xor(ls, 32);
  const float inv = 1.f / ls;
  const int q = qb + lr;
#pragma unroll
  for (int df = 0; df < 4; ++df) {
    ushort4 o4;
    o4.x = bfc(oacc[df][0] * inv);
    o4.y = bfc(oacc[df][1] * inv);
    o4.z = bfc(oacc[df][2] * inv);
    o4.w = bfc(oacc[df][3] * inv);
    *reinterpret_cast<ushort4*>(
        &Ob[((size_t)(b * 2048 + q)) * 1024 + h * 64 + df * 16 + 4 * lg]) = o4;
  }
}

// ------------------------------------------------------------------ launch
extern "C" void kernel_launch(void* const* d_in, const int* in_sizes, int n_in,
                              void* d_out, int out_size, void* d_ws, size_t ws_size,
                              hipStream_t stream) {
  const float* x  = (const float*)d_in[0];
  const float* Wq = (const float*)d_in[1];
  const float* bq = (const float*)d_in[2];
  const float* Wk = (const float*)d_in[3];
  const float* bk = (const float*)d_in[4];
  const float* Wv = (const float*)d_in[5];
  const float* bv = (const float*)d_in[6];
  const float* Wo = (const float*)d_in[7];
  const float* bo = (const float*)d_in[8];
  float* out = (float*)d_out;

  unsigned short* xb  = (unsigned short*)d_ws;          // 4096*1024
  unsigned short* wqt = xb  + 4096 * 1024;              // 1024*1024 each
  unsigned short* wkt = wqt + 1024 * 1024;
  unsigned short* wvt = wkt + 1024 * 1024;
  unsigned short* wot = wvt + 1024 * 1024;
  unsigned short* Qh  = wot + 1024 * 1024;              // [b,h,s,d]
  unsigned short* Kh  = Qh  + 4096 * 1024;
  unsigned short* Vh  = Kh  + 4096 * 1024;
  unsigned short* Vt  = Vh  + 4096 * 1024;              // [b,h,d,s]
  unsigned short* Ob  = Vt  + 4096 * 1024;              // [4096][1024]

  cast_x_kernel<<<4096, 256, 0, stream>>>(x, xb);
  cast_wt_kernel<<<dim3(16, 16, 4), 256, 0, stream>>>(Wq, Wk, Wv, Wo, wqt, wkt, wvt, wot);
  gemm128<0><<<dim3(32, 24), 256, 0, stream>>>(xb, wqt, wkt, wvt, bq, bk, bv,
                                               Qh, Kh, Vh, nullptr);
  transpose_v_kernel<<<dim3(32, 32), 256, 0, stream>>>(Vh, Vt);
  attn_kernel<<<1024, 256, 0, stream>>>(Qh, Kh, Vt, Ob);
  gemm128<1><<<dim3(32, 8), 256, 0, stream>>>(Ob, wot, nullptr, nullptr, bo, nullptr, nullptr,
                                              nullptr, nullptr, nullptr, out);
}

// Round 6
// 120.778 us; speedup vs baseline: 2.5072x; 1.0038x over previous
//
#include <hip/hip_runtime.h>

// Masked causal MHA: B=2, S=2048, E=1024, H=16, D=64.
// ws layout (bf16/ushort): xb[4096*1024] | wqt|wkt|wvt|wot[1024*1024 each, [N][K]]
//   | Qh|Kh|Vh(unused) [b,h,s,d] | Vt [b,h,d,s] | Ob [4096][1024].

using f32x4  = __attribute__((ext_vector_type(4))) float;
using bf16x8 = __attribute__((ext_vector_type(8))) __bf16;
using u16x8  = __attribute__((ext_vector_type(8))) unsigned short;
using u32x4  = __attribute__((ext_vector_type(4))) unsigned int;

__device__ __forceinline__ unsigned short f2bf(float f) {
  unsigned u = __float_as_uint(f);
  u += 0x7fff + ((u >> 16) & 1u);            // round-to-nearest-even
  return (unsigned short)(u >> 16);
}

__device__ __forceinline__ unsigned short bfc(float f) {   // HW cvt
  __bf16 h = (__bf16)f;
  return __builtin_bit_cast(unsigned short, h);
}

__device__ __forceinline__ bf16x8 ld_bf8(const unsigned short* p) {
  return __builtin_bit_cast(bf16x8, *reinterpret_cast<const u16x8*>(p));
}

#define GLDS16(gp, lp)                                                        \
  __builtin_amdgcn_global_load_lds(                                           \
      (__attribute__((address_space(1))) void*)(gp),                          \
      (__attribute__((address_space(3))) void*)(lp), 16, 0, 0)

// ------------------------------------------- prep: cast x + transpose weights
// blocks 0..4095: cast x -> bf16. blocks 4096..5119: W[k][n] -> Wt[n][k] bf16.
__global__ void prep_kernel(const float* __restrict__ x,
                            const float* __restrict__ w0, const float* __restrict__ w1,
                            const float* __restrict__ w2, const float* __restrict__ w3,
                            unsigned short* __restrict__ xb,
                            unsigned short* __restrict__ t0, unsigned short* __restrict__ t1,
                            unsigned short* __restrict__ t2, unsigned short* __restrict__ t3) {
  __shared__ float tile[64][65];
  const int t = threadIdx.x;
  const int bid = blockIdx.x;
  if (bid < 4096) {
    const int i = (bid * 256 + t) * 4;
    const float4 v = *reinterpret_cast<const float4*>(x + i);
    ushort4 o;
    o.x = f2bf(v.x); o.y = f2bf(v.y); o.z = f2bf(v.z); o.w = f2bf(v.w);
    *reinterpret_cast<ushort4*>(xb + i) = o;
    return;
  }
  const int q0 = bid - 4096;
  const int wsel = q0 >> 8, rem = q0 & 255;
  const float* src; unsigned short* dst;
  switch (wsel) {
    case 0:  src = w0; dst = t0; break;
    case 1:  src = w1; dst = t1; break;
    case 2:  src = w2; dst = t2; break;
    default: src = w3; dst = t3; break;
  }
  const int n0 = (rem & 15) * 64, k0 = (rem >> 4) * 64;
#pragma unroll
  for (int i = 0; i < 4; ++i) {               // load 64x64 fp32 tile, rows = k
    const int q = t + i * 256, r = q >> 4, c4 = q & 15;
    const float4 v = *reinterpret_cast<const float4*>(src + (k0 + r) * 1024 + n0 + c4 * 4);
    tile[r][c4 * 4 + 0] = v.x; tile[r][c4 * 4 + 1] = v.y;
    tile[r][c4 * 4 + 2] = v.z; tile[r][c4 * 4 + 3] = v.w;
  }
  __syncthreads();
#pragma unroll
  for (int i = 0; i < 4; ++i) {               // write Wt[n][k] bf16
    const int q = t + i * 256, n = q >> 4, c4 = q & 15;
    ushort4 o;
    o.x = f2bf(tile[c4 * 4 + 0][n]); o.y = f2bf(tile[c4 * 4 + 1][n]);
    o.z = f2bf(tile[c4 * 4 + 2][n]); o.w = f2bf(tile[c4 * 4 + 3][n]);
    *reinterpret_cast<ushort4*>(dst + (n0 + n) * 1024 + k0 + c4 * 4) = o;
  }
}

// ------------------------------------- QKV GEMM: 256x256 tile, deep pipeline
// 8 waves (2M x 4N), K sub-tiles of 32 in a 4-slot LDS ring (128 KB).
// Stage tile T+3 while computing T (slots disjoint); counted vmcnt(8) at tile
// boundaries (never 0); raw s_barrier; 2 phases x 16 MFMA per tile.
// Q pre-scaled by 0.125*log2e; V written transposed to Vt [b,h,d,s].
__global__ __launch_bounds__(512, 1) void gemm256_qkv(
    const unsigned short* __restrict__ A,
    const unsigned short* __restrict__ BtQ, const unsigned short* __restrict__ BtK,
    const unsigned short* __restrict__ BtV,
    const float* __restrict__ biasQ, const float* __restrict__ biasK,
    const float* __restrict__ biasV,
    unsigned short* __restrict__ OQ, unsigned short* __restrict__ OK_,
    unsigned short* __restrict__ OVt) {
  __shared__ unsigned short As[4][256 * 32];  // [slot][row m][k 32], swizzled
  __shared__ unsigned short Bs[4][256 * 32];  // [slot][row n][k 32], swizzled

  const int bid0 = blockIdx.x;                // 192 blocks
  const int bid = (bid0 & 7) * 24 + (bid0 >> 3);   // bijective XCD swizzle
  const int ntile = bid >> 4;                 // 0..11
  const int mtile = bid & 15;                 // 0..15
  const int which = ntile >> 2;               // 0=Q 1=K 2=V
  const unsigned short* Bt = (which == 0) ? BtQ : (which == 1) ? BtK : BtV;
  const float* bias = (which == 0) ? biasQ : (which == 1) ? biasK : biasV;
  const int nn = (ntile & 3) * 256;           // n offset within weight
  const int m0 = mtile * 256;

  const int tid = threadIdx.x;
  const int w = tid >> 6, l = tid & 63;
  const int wm = (w >> 2) * 128, wn = (w & 3) * 64;
  const int lr = l & 15, lg = l >> 4;

  f32x4 acc[8][4];
#pragma unroll
  for (int i = 0; i < 8; ++i)
#pragma unroll
    for (int j = 0; j < 4; ++j) acc[i][j] = f32x4{0.f, 0.f, 0.f, 0.f};

  auto stA = [&](int kt) {
    const int s = kt & 3;
#pragma unroll
    for (int p = 0; p < 2; ++p) {
      const int o = tid * 16 + p * 8192;      // linear byte offset in 16KB
      const int row = o >> 6, cb = o & 63;
      const int scb = cb ^ (((row >> 1) & 3) << 4);   // pre-swizzled src col
      GLDS16(A + (size_t)(m0 + row) * 1024 + kt * 32 + (scb >> 1),
             ((char*)As[s]) + o);
    }
  };
  auto stB = [&](int kt) {
    const int s = kt & 3;
#pragma unroll
    for (int p = 0; p < 2; ++p) {
      const int o = tid * 16 + p * 8192;
      const int row = o >> 6, cb = o & 63;
      const int scb = cb ^ (((row >> 1) & 3) << 4);
      GLDS16(Bt + (size_t)(nn + row) * 1024 + kt * 32 + (scb >> 1),
             ((char*)Bs[s]) + o);
    }
  };

  // prologue: stage tiles 0,1,2 (12 loads/thread), wait for tile 0 (<=8 left)
  stA(0); stB(0); stA(1); stB(1); stA(2); stB(2);
  asm volatile("s_waitcnt vmcnt(8)" ::: "memory");
  __builtin_amdgcn_s_barrier();

  for (int kt = 0; kt < 32; ++kt) {
    const int s = kt & 3;
    const unsigned short* as = As[s];
    const unsigned short* bs = Bs[s];
    bf16x8 bfr[4], af[4];
    // ---- phase 0: m-half 0
#pragma unroll
    for (int nf = 0; nf < 4; ++nf) {
      const int row = wn + nf * 16 + lr;
      bfr[nf] = ld_bf8(bs + row * 32 + (lg * 8 ^ (((row >> 1) & 3) << 3)));
    }
#pragma unroll
    for (int mi = 0; mi < 4; ++mi) {
      const int row = wm + mi * 16 + lr;
      af[mi] = ld_bf8(as + row * 32 + (lg * 8 ^ (((row >> 1) & 3) << 3)));
    }
    if (kt + 3 < 32) stA(kt + 3);
    asm volatile("" ::: "memory");
    __builtin_amdgcn_s_barrier();
    asm volatile("s_waitcnt lgkmcnt(0)" ::: "memory");
    __builtin_amdgcn_sched_barrier(0);
    __builtin_amdgcn_s_setprio(1);
#pragma unroll
    for (int mi = 0; mi < 4; ++mi)
#pragma unroll
      for (int nf = 0; nf < 4; ++nf)
        acc[mi][nf] = __builtin_amdgcn_mfma_f32_16x16x32_bf16(af[mi], bfr[nf], acc[mi][nf], 0, 0, 0);
    __builtin_amdgcn_s_setprio(0);
    __builtin_amdgcn_s_barrier();
    // ---- phase 1: m-half 1 (B frags reused)
#pragma unroll
    for (int mi = 0; mi < 4; ++mi) {
      const int row = wm + 64 + mi * 16 + lr;
      af[mi] = ld_bf8(as + row * 32 + (lg * 8 ^ (((row >> 1) & 3) << 3)));
    }
    if (kt + 3 < 32) stB(kt + 3);
    asm volatile("" ::: "memory");
    __builtin_amdgcn_s_barrier();
    asm volatile("s_waitcnt lgkmcnt(0)" ::: "memory");
    __builtin_amdgcn_sched_barrier(0);
    __builtin_amdgcn_s_setprio(1);
#pragma unroll
    for (int mi = 0; mi < 4; ++mi)
#pragma unroll
      for (int nf = 0; nf < 4; ++nf)
        acc[4 + mi][nf] = __builtin_amdgcn_mfma_f32_16x16x32_bf16(af[mi], bfr[nf], acc[4 + mi][nf], 0, 0, 0);
    __builtin_amdgcn_s_setprio(0);
    // ---- tile boundary: next tile's slot landed when <=8 loads outstanding
    asm volatile("s_waitcnt vmcnt(8)" ::: "memory");
    __builtin_amdgcn_s_barrier();
  }

  // ---- epilogue
  const float SC = (which == 0) ? 0.18033688f : 1.0f;   // 0.125*log2(e) for Q
  unsigned short* Oqk = (which == 0) ? OQ : OK_;
#pragma unroll
  for (int nf = 0; nf < 4; ++nf) {
    const int n = nn + wn + nf * 16 + lr;     // [0,1024) within weight
    const float bv = bias[n];
    const int hh = n >> 6, dd = n & 63;
#pragma unroll
    for (int mi = 0; mi < 8; ++mi) {
      const int mB = m0 + wm + mi * 16 + 4 * lg;   // + r
      const int bb = mB >> 11, sloc = mB & 2047;
      if (which == 2) {                       // V -> Vt [b,h,d,s], 8B stores
        ushort4 o4;
        o4.x = bfc(acc[mi][nf][0] + bv);
        o4.y = bfc(acc[mi][nf][1] + bv);
        o4.z = bfc(acc[mi][nf][2] + bv);
        o4.w = bfc(acc[mi][nf][3] + bv);
        *reinterpret_cast<ushort4*>(
            &OVt[(((size_t)(bb * 16 + hh)) * 64 + dd) * 2048 + sloc]) = o4;
      } else {
#pragma unroll
        for (int r = 0; r < 4; ++r) {
          const float v = (acc[mi][nf][r] + bv) * SC;
          Oqk[(((size_t)(bb * 16 + hh)) * 2048 + sloc + r) * 64 + dd] = f2bf(v);
        }
      }
    }
  }
}

// ------------------------------------------------------- output-proj GEMM
// C[4096][1024] = Ob @ Wot^T + bo (fp32 out). 128x128 tile, BK=64, 4 waves.
__global__ __launch_bounds__(256, 3) void gemm_out(
    const unsigned short* __restrict__ A, const unsigned short* __restrict__ Bt,
    const float* __restrict__ bias, float* __restrict__ OF) {
  __shared__ unsigned short As[128 * 64];
  __shared__ unsigned short Bs[128 * 64];

  const int m0 = blockIdx.x * 128;
  const int nloc0 = blockIdx.y * 128;
  const int t = threadIdx.x;
  const int w = t >> 6, l = t & 63;
  const int wm = (w >> 1) * 64, wn = (w & 1) * 64;
  const int lr = l & 15, lg = l >> 4;

  f32x4 acc[4][4];
#pragma unroll
  for (int i = 0; i < 4; ++i)
#pragma unroll
    for (int j = 0; j < 4; ++j) acc[i][j] = f32x4{0.f, 0.f, 0.f, 0.f};

  for (int k0 = 0; k0 < 1024; k0 += 64) {
#pragma unroll
    for (int i = 0; i < 4; ++i) {             // stage A tile: [128 m][64 k]
      const int off = t * 16 + i * 4096;
      const int r = off >> 7, cb = off & 127;
      GLDS16(A + (m0 + r) * 1024 + k0 + (cb >> 1), ((char*)As) + off);
    }
#pragma unroll
    for (int i = 0; i < 4; ++i) {             // stage B tile: [128 n][64 k]
      const int off = t * 16 + i * 4096;
      const int r = off >> 7, cb = off & 127;
      GLDS16(Bt + (nloc0 + r) * 1024 + k0 + (cb >> 1), ((char*)Bs) + off);
    }
    __syncthreads();
#pragma unroll
    for (int kk = 0; kk < 2; ++kk) {
      bf16x8 af[4], bfr[4];
#pragma unroll
      for (int mi = 0; mi < 4; ++mi)
        af[mi] = ld_bf8(As + (wm + mi * 16 + lr) * 64 + kk * 32 + lg * 8);
#pragma unroll
      for (int ni = 0; ni < 4; ++ni)
        bfr[ni] = ld_bf8(Bs + (wn + ni * 16 + lr) * 64 + kk * 32 + lg * 8);
#pragma unroll
      for (int mi = 0; mi < 4; ++mi)
#pragma unroll
        for (int ni = 0; ni < 4; ++ni)
          acc[mi][ni] = __builtin_amdgcn_mfma_f32_16x16x32_bf16(af[mi], bfr[ni], acc[mi][ni], 0, 0, 0);
    }
    __syncthreads();
  }

#pragma unroll
  for (int ni = 0; ni < 4; ++ni) {
    const int n = nloc0 + wn + ni * 16 + lr;
    const float bv = bias[n];
#pragma unroll
    for (int mi = 0; mi < 4; ++mi) {
#pragma unroll
      for (int r = 0; r < 4; ++r) {
        const int m = m0 + wm + mi * 16 + 4 * lg + r;
        OF[m * 1024 + n] = acc[mi][ni][r] + bv;
      }
    }
  }
}

// ------------------------------------------------------- flash attention v5
// 64-row q-blocks (1024 blocks), swapped QK^T, in-register softmax, defer-max,
// per-lane partial l, LPT grid order. (unchanged from R5)
__global__ __launch_bounds__(256, 4) void attn_kernel(
    const unsigned short* __restrict__ Qh, const unsigned short* __restrict__ Kh,
    const unsigned short* __restrict__ Vt, unsigned short* __restrict__ Ob) {
  const int g = blockIdx.x;
  const int qt = 31 - (g >> 5);              // LPT: longest first
  const int bh = g & 31;
  const int b = bh >> 4, h = bh & 15;
  const int t = threadIdx.x, w = t >> 6, l = t & 63;
  const int lr = l & 15, lg = l >> 4;
  const int sl0 = lr + 32 * (lg & 1);        // pack-shuffle source lanes
  const int sl1 = sl0 + 16;
  const bool hi2 = (l & 32) != 0;

  __shared__ unsigned short Kb[2][4096];     // [64 kv][64 d], swizzled
  __shared__ unsigned short Vb[2][4096];     // [64 d][64 kv], swizzled

  const unsigned short* Kbase = Kh + (size_t)bh * (2048 * 64);
  const unsigned short* Vbase = Vt + (size_t)bh * (64 * 2048);

  const int qb = qt * 64 + w * 16;           // this wave's 16 q rows
  const unsigned short* Qp = Qh + ((size_t)bh * 2048 + qb + lr) * 64;
  bf16x8 qf[2];
  qf[0] = ld_bf8(Qp + lg * 8);
  qf[1] = ld_bf8(Qp + 32 + lg * 8);

  f32x4 oacc[4];                             // O^T: lane q=qb+lr, d=df*16+4lg+r
#pragma unroll
  for (int i = 0; i < 4; ++i) oacc[i] = f32x4{0.f, 0.f, 0.f, 0.f};
  float mrun = -3e38f;
  float lpart = 0.f;                         // per-lane partial denominator

  auto stage = [&](int kv0, int bi) {
#pragma unroll
    for (int p = 0; p < 2; ++p) {
      const int o = t * 16 + p * 4096;       // linear byte offset in 8KB tile
      const int row = o >> 7;
      const int scb = (o & 127) ^ ((row & 7) << 4);   // pre-swizzled src col
      GLDS16(Kbase + (size_t)(kv0 + row) * 64 + (scb >> 1), ((char*)Kb[bi]) + o);
      GLDS16(Vbase + (size_t)row * 2048 + kv0 + (scb >> 1), ((char*)Vb[bi]) + o);
    }
  };

  const int nt = qt + 1;
  stage(0, 0);
  __syncthreads();

  for (int ti = 0; ti < nt; ++ti) {
    const int cur = ti & 1;
    const int kv0 = ti * 64;
    if (ti + 1 < nt) stage((ti + 1) * 64, cur ^ 1);

    // ---- QK^T (swapped: S^T = K . Q^T)
    f32x4 s[4];
#pragma unroll
    for (int i = 0; i < 4; ++i) s[i] = f32x4{0.f, 0.f, 0.f, 0.f};
    __builtin_amdgcn_s_setprio(1);
#pragma unroll
    for (int kf = 0; kf < 2; ++kf) {
#pragma unroll
      for (int nf = 0; nf < 4; ++nf) {
        const int row = nf * 16 + lr;
        const int col = (kf * 32 + lg * 8) ^ ((row & 7) << 3);
        const bf16x8 kb = ld_bf8(&Kb[cur][row * 64 + col]);
        s[nf] = __builtin_amdgcn_mfma_f32_16x16x32_bf16(kb, qf[kf], s[nf], 0, 0, 0);
      }
    }
    __builtin_amdgcn_s_setprio(0);

    // ---- softmax (no cross-lane ops on common path)
    if (ti == qt) {                          // diagonal tile: causal mask
#pragma unroll
      for (int nf = 0; nf < 4; ++nf) {
        const int kv = kv0 + nf * 16 + 4 * lg;
#pragma unroll
        for (int r = 0; r < 4; ++r)
          if (kv + r > qb + lr) s[nf][r] = -3e38f;
      }
    }
    float m01 = -3e38f, m23 = -3e38f;        // balanced per-lane max tree
#pragma unroll
    for (int r = 0; r < 4; ++r) {
      m01 = fmaxf(m01, fmaxf(s[0][r], s[1][r]));
      m23 = fmaxf(m23, fmaxf(s[2][r], s[3][r]));
    }
    const float mx = fmaxf(m01, m23);
    if (!__all(mx <= mrun + 8.f)) {          // defer-max (T13)
      float m0 = fmaxf(mx, __shfl_xor(mx, 16));
      m0 = fmaxf(m0, __shfl_xor(m0, 32));
      const float n0 = fmaxf(mrun, m0);
      const float c0 = __builtin_amdgcn_exp2f(mrun - n0);
      mrun = n0;
      lpart *= c0;
#pragma unroll
      for (int df = 0; df < 4; ++df)
#pragma unroll
        for (int r = 0; r < 4; ++r) oacc[df][r] *= c0;
    }
    float rs[4] = {0.f, 0.f, 0.f, 0.f};      // 4 independent partial sums
#pragma unroll
    for (int nf = 0; nf < 4; ++nf)
#pragma unroll
      for (int r = 0; r < 4; ++r) {
        const float p = __builtin_amdgcn_exp2f(s[nf][r] - mrun);
        s[nf][r] = p;
        rs[nf] += p;
      }
    lpart += (rs[0] + rs[1]) + (rs[2] + rs[3]);

    // ---- pack P^T into PV B-operand fragments (in registers)
    unsigned wpk[4][2];
#pragma unroll
    for (int nf = 0; nf < 4; ++nf) {
      asm("v_cvt_pk_bf16_f32 %0, %1, %2" : "=v"(wpk[nf][0]) : "v"(s[nf][0]), "v"(s[nf][1]));
      asm("v_cvt_pk_bf16_f32 %0, %1, %2" : "=v"(wpk[nf][1]) : "v"(s[nf][2]), "v"(s[nf][3]));
    }
    bf16x8 pa[2];
#pragma unroll
    for (int kf = 0; kf < 2; ++kf) {
      const unsigned a0w = __shfl(wpk[2 * kf][0], sl0), b0w = __shfl(wpk[2 * kf + 1][0], sl0);
      const unsigned a1w = __shfl(wpk[2 * kf][1], sl0), b1w = __shfl(wpk[2 * kf + 1][1], sl0);
      const unsigned a2w = __shfl(wpk[2 * kf][0], sl1), b2w = __shfl(wpk[2 * kf + 1][0], sl1);
      const unsigned a3w = __shfl(wpk[2 * kf][1], sl1), b3w = __shfl(wpk[2 * kf + 1][1], sl1);
      u32x4 uu;
      uu[0] = hi2 ? b0w : a0w;
      uu[1] = hi2 ? b1w : a1w;
      uu[2] = hi2 ? b2w : a2w;
      uu[3] = hi2 ? b3w : a3w;
      pa[kf] = __builtin_bit_cast(bf16x8, uu);
    }

    // ---- PV: O^T += V^T . P^T
    __builtin_amdgcn_s_setprio(1);
#pragma unroll
    for (int kf = 0; kf < 2; ++kf) {
#pragma unroll
      for (int df = 0; df < 4; ++df) {
        const int vrow = df * 16 + lr;
        const int vcol = (kf * 32 + lg * 8) ^ ((vrow & 7) << 3);
        const bf16x8 vb = ld_bf8(&Vb[cur][vrow * 64 + vcol]);
        oacc[df] = __builtin_amdgcn_mfma_f32_16x16x32_bf16(vb, pa[kf], oacc[df], 0, 0, 0);
      }
    }
    __builtin_amdgcn_s_setprio(0);
    __syncthreads();                         // drains prefetch + guards buffers
  }

  float ls = lpart;
  ls += __shfl_xor(ls, 16);
  ls += __shfl_xor(ls, 32);
  const float inv = 1.f / ls;
  const int q = qb + lr;
#pragma unroll
  for (int df = 0; df < 4; ++df) {
    ushort4 o4;
    o4.x = bfc(oacc[df][0] * inv);
    o4.y = bfc(oacc[df][1] * inv);
    o4.z = bfc(oacc[df][2] * inv);
    o4.w = bfc(oacc[df][3] * inv);
    *reinterpret_cast<ushort4*>(
        &Ob[((size_t)(b * 2048 + q)) * 1024 + h * 64 + df * 16 + 4 * lg]) = o4;
  }
}

// ------------------------------------------------------------------ launch
extern "C" void kernel_launch(void* const* d_in, const int* in_sizes, int n_in,
                              void* d_out, int out_size, void* d_ws, size_t ws_size,
                              hipStream_t stream) {
  const float* x  = (const float*)d_in[0];
  const float* Wq = (const float*)d_in[1];
  const float* bq = (const float*)d_in[2];
  const float* Wk = (const float*)d_in[3];
  const float* bk = (const float*)d_in[4];
  const float* Wv = (const float*)d_in[5];
  const float* bv = (const float*)d_in[6];
  const float* Wo = (const float*)d_in[7];
  const float* bo = (const float*)d_in[8];
  float* out = (float*)d_out;

  unsigned short* xb  = (unsigned short*)d_ws;          // 4096*1024
  unsigned short* wqt = xb  + 4096 * 1024;              // 1024*1024 each
  unsigned short* wkt = wqt + 1024 * 1024;
  unsigned short* wvt = wkt + 1024 * 1024;
  unsigned short* wot = wvt + 1024 * 1024;
  unsigned short* Qh  = wot + 1024 * 1024;              // [b,h,s,d]
  unsigned short* Kh  = Qh  + 4096 * 1024;
  unsigned short* Vh  = Kh  + 4096 * 1024;              // (unused)
  unsigned short* Vt  = Vh  + 4096 * 1024;              // [b,h,d,s]
  unsigned short* Ob  = Vt  + 4096 * 1024;              // [4096][1024]

  prep_kernel<<<5120, 256, 0, stream>>>(x, Wq, Wk, Wv, Wo, xb, wqt, wkt, wvt, wot);
  gemm256_qkv<<<192, 512, 0, stream>>>(xb, wqt, wkt, wvt, bq, bk, bv, Qh, Kh, Vt);
  attn_kernel<<<1024, 256, 0, stream>>>(Qh, Kh, Vt, Ob);
  gemm_out<<<dim3(32, 8), 256, 0, stream>>>(Ob, wot, bo, out);
}

// Round 7
// 113.316 us; speedup vs baseline: 2.6723x; 1.0659x over previous
//
#include <hip/hip_runtime.h>

// Masked causal MHA: B=2, S=2048, E=1024, H=16, D=64.
// ws layout (bf16/ushort): xb[4096*1024] | wqt|wkt|wvt|wot[1024*1024 each, [N][K]]
//   | Qh|Kh|Vh(unused) [b,h,s,d] | Vt [b,h,d,s] | Ob [4096][1024].

using f32x4  = __attribute__((ext_vector_type(4))) float;
using bf16x8 = __attribute__((ext_vector_type(8))) __bf16;
using u16x8  = __attribute__((ext_vector_type(8))) unsigned short;
using u32x4  = __attribute__((ext_vector_type(4))) unsigned int;

__device__ __forceinline__ unsigned short f2bf(float f) {
  unsigned u = __float_as_uint(f);
  u += 0x7fff + ((u >> 16) & 1u);            // round-to-nearest-even
  return (unsigned short)(u >> 16);
}

__device__ __forceinline__ unsigned short bfc(float f) {   // HW cvt
  __bf16 h = (__bf16)f;
  return __builtin_bit_cast(unsigned short, h);
}

__device__ __forceinline__ bf16x8 ld_bf8(const unsigned short* p) {
  return __builtin_bit_cast(bf16x8, *reinterpret_cast<const u16x8*>(p));
}

#define GLDS16(gp, lp)                                                        \
  __builtin_amdgcn_global_load_lds(                                           \
      (__attribute__((address_space(1))) void*)(gp),                          \
      (__attribute__((address_space(3))) void*)(lp), 16, 0, 0)

// ------------------------------------------- prep: cast x + transpose weights
// blocks 0..4095: cast x -> bf16. blocks 4096..5119: W[k][n] -> Wt[n][k] bf16.
__global__ void prep_kernel(const float* __restrict__ x,
                            const float* __restrict__ w0, const float* __restrict__ w1,
                            const float* __restrict__ w2, const float* __restrict__ w3,
                            unsigned short* __restrict__ xb,
                            unsigned short* __restrict__ t0, unsigned short* __restrict__ t1,
                            unsigned short* __restrict__ t2, unsigned short* __restrict__ t3) {
  __shared__ float tile[64][65];
  const int t = threadIdx.x;
  const int bid = blockIdx.x;
  if (bid < 4096) {
    const int i = (bid * 256 + t) * 4;
    const float4 v = *reinterpret_cast<const float4*>(x + i);
    ushort4 o;
    o.x = f2bf(v.x); o.y = f2bf(v.y); o.z = f2bf(v.z); o.w = f2bf(v.w);
    *reinterpret_cast<ushort4*>(xb + i) = o;
    return;
  }
  const int q0 = bid - 4096;
  const int wsel = q0 >> 8, rem = q0 & 255;
  const float* src; unsigned short* dst;
  switch (wsel) {
    case 0:  src = w0; dst = t0; break;
    case 1:  src = w1; dst = t1; break;
    case 2:  src = w2; dst = t2; break;
    default: src = w3; dst = t3; break;
  }
  const int n0 = (rem & 15) * 64, k0 = (rem >> 4) * 64;
#pragma unroll
  for (int i = 0; i < 4; ++i) {               // load 64x64 fp32 tile, rows = k
    const int q = t + i * 256, r = q >> 4, c4 = q & 15;
    const float4 v = *reinterpret_cast<const float4*>(src + (k0 + r) * 1024 + n0 + c4 * 4);
    tile[r][c4 * 4 + 0] = v.x; tile[r][c4 * 4 + 1] = v.y;
    tile[r][c4 * 4 + 2] = v.z; tile[r][c4 * 4 + 3] = v.w;
  }
  __syncthreads();
#pragma unroll
  for (int i = 0; i < 4; ++i) {               // write Wt[n][k] bf16
    const int q = t + i * 256, n = q >> 4, c4 = q & 15;
    ushort4 o;
    o.x = f2bf(tile[c4 * 4 + 0][n]); o.y = f2bf(tile[c4 * 4 + 1][n]);
    o.z = f2bf(tile[c4 * 4 + 2][n]); o.w = f2bf(tile[c4 * 4 + 3][n]);
    *reinterpret_cast<ushort4*>(dst + (n0 + n) * 1024 + k0 + c4 * 4) = o;
  }
}

// ------------------------------------------------------------------- GEMM
// C[M=4096][N] = A[M][1024] @ Bt^T (+ bias). Bt is [N][K]. 128x128 tile, BK=64,
// 4 waves of 64x64. MODE 0: fused QKV — Q scaled by 0.125*log2e to [b,h,s,d],
// K to [b,h,s,d], V transposed to Vt [b,h,d,s]. MODE 1: O-proj, fp32 out.
template <int MODE>
__global__ __launch_bounds__(256, 2) void gemm128(
    const unsigned short* __restrict__ A,
    const unsigned short* __restrict__ BtQ, const unsigned short* __restrict__ BtK,
    const unsigned short* __restrict__ BtV,
    const float* __restrict__ biasQ, const float* __restrict__ biasK,
    const float* __restrict__ biasV,
    unsigned short* __restrict__ OQ, unsigned short* __restrict__ OK_,
    unsigned short* __restrict__ OVt, float* __restrict__ OF) {
  __shared__ unsigned short As[128 * 64];
  __shared__ unsigned short Bs[128 * 64];

  const int mt = blockIdx.x, nt = blockIdx.y;
  const unsigned short* Bt; const float* bias;
  int nloc0, which = 0;
  if (MODE == 0) {
    which = nt >> 3;
    nloc0 = (nt & 7) * 128;
    Bt   = (which == 0) ? BtQ   : (which == 1) ? BtK   : BtV;
    bias = (which == 0) ? biasQ : (which == 1) ? biasK : biasV;
  } else {
    nloc0 = nt * 128;
    Bt = BtQ; bias = biasQ;
  }
  const int m0 = mt * 128;
  const int t = threadIdx.x;
  const int w = t >> 6, l = t & 63;
  const int wm = (w >> 1) * 64, wn = (w & 1) * 64;
  const int lr = l & 15, lg = l >> 4;

  f32x4 acc[4][4];
#pragma unroll
  for (int i = 0; i < 4; ++i)
#pragma unroll
    for (int j = 0; j < 4; ++j) acc[i][j] = f32x4{0.f, 0.f, 0.f, 0.f};

  for (int k0 = 0; k0 < 1024; k0 += 64) {
#pragma unroll
    for (int i = 0; i < 4; ++i) {             // stage A tile: [128 m][64 k]
      const int off = t * 16 + i * 4096;
      const int r = off >> 7, cb = off & 127;
      GLDS16(A + (m0 + r) * 1024 + k0 + (cb >> 1), ((char*)As) + off);
    }
#pragma unroll
    for (int i = 0; i < 4; ++i) {             // stage B tile: [128 n][64 k]
      const int off = t * 16 + i * 4096;
      const int r = off >> 7, cb = off & 127;
      GLDS16(Bt + (nloc0 + r) * 1024 + k0 + (cb >> 1), ((char*)Bs) + off);
    }
    __syncthreads();
#pragma unroll
    for (int kk = 0; kk < 2; ++kk) {
      bf16x8 af[4], bfr[4];
#pragma unroll
      for (int mi = 0; mi < 4; ++mi)
        af[mi] = ld_bf8(As + (wm + mi * 16 + lr) * 64 + kk * 32 + lg * 8);
#pragma unroll
      for (int ni = 0; ni < 4; ++ni)
        bfr[ni] = ld_bf8(Bs + (wn + ni * 16 + lr) * 64 + kk * 32 + lg * 8);
#pragma unroll
      for (int mi = 0; mi < 4; ++mi)
#pragma unroll
        for (int ni = 0; ni < 4; ++ni)
          acc[mi][ni] = __builtin_amdgcn_mfma_f32_16x16x32_bf16(af[mi], bfr[ni], acc[mi][ni], 0, 0, 0);
    }
    __syncthreads();
  }

  const float scl = (MODE == 0 && which == 0) ? 0.18033688f : 1.0f;  // Q scale
#pragma unroll
  for (int ni = 0; ni < 4; ++ni) {
    const int n = nloc0 + wn + ni * 16 + lr;  // column within this weight
    const float bv = bias[n];
#pragma unroll
    for (int mi = 0; mi < 4; ++mi) {
      const int mB = m0 + wm + mi * 16 + 4 * lg;
      if (MODE == 0 && which == 2) {          // V -> Vt [b,h,d,s], 8B stores
        const int bb = mB >> 11, sloc = mB & 2047;
        const int hh = n >> 6, dd = n & 63;
        ushort4 o4;
        o4.x = bfc(acc[mi][ni][0] + bv);
        o4.y = bfc(acc[mi][ni][1] + bv);
        o4.z = bfc(acc[mi][ni][2] + bv);
        o4.w = bfc(acc[mi][ni][3] + bv);
        *reinterpret_cast<ushort4*>(
            &OVt[(((size_t)(bb * 16 + hh)) * 64 + dd) * 2048 + sloc]) = o4;
      } else {
#pragma unroll
        for (int r = 0; r < 4; ++r) {
          const int m = mB + r;
          const float v = (acc[mi][ni][r] + bv) * scl;
          if (MODE == 0) {
            const int bb = m >> 11, sloc = m & 2047;
            const int hh = n >> 6, dd = n & 63;
            unsigned short* Oqk = (which == 0) ? OQ : OK_;
            Oqk[(((size_t)(bb * 16 + hh)) * 2048 + sloc) * 64 + dd] = f2bf(v);
          } else {
            OF[m * 1024 + n] = v;
          }
        }
      }
    }
  }
}

// ------------------------------------------------------- flash attention v6
// 64-row q-blocks (1024 blocks, 4 blocks/CU). Swapped QK^T, in-register
// softmax, defer-max, per-lane partial l. NEW: PV lags one tile — V/P frags
// held in registers, so the 8 PV MFMAs overlap the next tile's softmax VALU.
__global__ __launch_bounds__(256, 4) void attn_kernel(
    const unsigned short* __restrict__ Qh, const unsigned short* __restrict__ Kh,
    const unsigned short* __restrict__ Vt, unsigned short* __restrict__ Ob) {
  const int g = blockIdx.x;
  const int qt = 31 - (g >> 5);              // LPT: longest first
  const int bh = g & 31;
  const int b = bh >> 4, h = bh & 15;
  const int t = threadIdx.x, w = t >> 6, l = t & 63;
  const int lr = l & 15, lg = l >> 4;
  const int sl0 = lr + 32 * (lg & 1);        // pack-shuffle source lanes
  const int sl1 = sl0 + 16;
  const bool hi2 = (l & 32) != 0;

  __shared__ unsigned short Kb[2][4096];     // [64 kv][64 d], swizzled
  __shared__ unsigned short Vb[2][4096];     // [64 d][64 kv], swizzled

  const unsigned short* Kbase = Kh + (size_t)bh * (2048 * 64);
  const unsigned short* Vbase = Vt + (size_t)bh * (64 * 2048);

  const int qb = qt * 64 + w * 16;           // this wave's 16 q rows
  const unsigned short* Qp = Qh + ((size_t)bh * 2048 + qb + lr) * 64;
  bf16x8 qf[2];
  qf[0] = ld_bf8(Qp + lg * 8);
  qf[1] = ld_bf8(Qp + 32 + lg * 8);

  f32x4 oacc[4];                             // O^T: lane q=qb+lr, d=df*16+4lg+r
#pragma unroll
  for (int i = 0; i < 4; ++i) oacc[i] = f32x4{0.f, 0.f, 0.f, 0.f};
  float mrun = -3e38f;
  float lpart = 0.f;                         // per-lane partial denominator

  bf16x8 vbp[2][4];                          // V frags of previous tile
  bf16x8 pap[2];                             // P frags of previous tile

  auto stage = [&](int kv0, int bi) {
#pragma unroll
    for (int p = 0; p < 2; ++p) {
      const int o = t * 16 + p * 4096;       // linear byte offset in 8KB tile
      const int row = o >> 7;
      const int scb = (o & 127) ^ ((row & 7) << 4);   // pre-swizzled src col
      GLDS16(Kbase + (size_t)(kv0 + row) * 64 + (scb >> 1), ((char*)Kb[bi]) + o);
      GLDS16(Vbase + (size_t)row * 2048 + kv0 + (scb >> 1), ((char*)Vb[bi]) + o);
    }
  };

  const int nt = qt + 1;
  stage(0, 0);
  __syncthreads();

  for (int ti = 0; ti < nt; ++ti) {
    const int cur = ti & 1;
    const int kv0 = ti * 64;
    if (ti + 1 < nt) stage((ti + 1) * 64, cur ^ 1);

    // ---- QK^T (swapped: S^T = K . Q^T)
    f32x4 s[4];
#pragma unroll
    for (int i = 0; i < 4; ++i) s[i] = f32x4{0.f, 0.f, 0.f, 0.f};
    __builtin_amdgcn_s_setprio(1);
#pragma unroll
    for (int kf = 0; kf < 2; ++kf) {
#pragma unroll
      for (int nf = 0; nf < 4; ++nf) {
        const int row = nf * 16 + lr;
        const int col = (kf * 32 + lg * 8) ^ ((row & 7) << 3);
        const bf16x8 kb = ld_bf8(&Kb[cur][row * 64 + col]);
        s[nf] = __builtin_amdgcn_mfma_f32_16x16x32_bf16(kb, qf[kf], s[nf], 0, 0, 0);
      }
    }
    // ---- PV of PREVIOUS tile (register operands; overlaps softmax below)
    if (ti > 0) {
#pragma unroll
      for (int kf = 0; kf < 2; ++kf)
#pragma unroll
        for (int df = 0; df < 4; ++df)
          oacc[df] = __builtin_amdgcn_mfma_f32_16x16x32_bf16(vbp[kf][df], pap[kf], oacc[df], 0, 0, 0);
    }
    __builtin_amdgcn_s_setprio(0);

    // ---- this tile's V frags -> registers (consumed next iteration)
#pragma unroll
    for (int kf = 0; kf < 2; ++kf)
#pragma unroll
      for (int df = 0; df < 4; ++df) {
        const int vrow = df * 16 + lr;
        const int vcol = (kf * 32 + lg * 8) ^ ((vrow & 7) << 3);
        vbp[kf][df] = ld_bf8(&Vb[cur][vrow * 64 + vcol]);
      }

    // ---- softmax (no cross-lane ops on common path)
    if (ti == qt) {                          // diagonal tile: causal mask
#pragma unroll
      for (int nf = 0; nf < 4; ++nf) {
        const int kv = kv0 + nf * 16 + 4 * lg;
#pragma unroll
        for (int r = 0; r < 4; ++r)
          if (kv + r > qb + lr) s[nf][r] = -3e38f;
      }
    }
    float m01 = -3e38f, m23 = -3e38f;        // balanced per-lane max tree
#pragma unroll
    for (int r = 0; r < 4; ++r) {
      m01 = fmaxf(m01, fmaxf(s[0][r], s[1][r]));
      m23 = fmaxf(m23, fmaxf(s[2][r], s[3][r]));
    }
    const float mx = fmaxf(m01, m23);
    if (!__all(mx <= mrun + 8.f)) {          // defer-max (T13); rare branch
      float m0 = fmaxf(mx, __shfl_xor(mx, 16));
      m0 = fmaxf(m0, __shfl_xor(m0, 32));
      const float n0 = fmaxf(mrun, m0);
      const float c0 = __builtin_amdgcn_exp2f(mrun - n0);
      mrun = n0;
      lpart *= c0;
#pragma unroll
      for (int df = 0; df < 4; ++df)
#pragma unroll
        for (int r = 0; r < 4; ++r) oacc[df][r] *= c0;
    }
    float rs[4] = {0.f, 0.f, 0.f, 0.f};      // 4 independent partial sums
#pragma unroll
    for (int nf = 0; nf < 4; ++nf)
#pragma unroll
      for (int r = 0; r < 4; ++r) {
        const float p = __builtin_amdgcn_exp2f(s[nf][r] - mrun);
        s[nf][r] = p;
        rs[nf] += p;
      }
    lpart += (rs[0] + rs[1]) + (rs[2] + rs[3]);

    // ---- pack P^T into PV B-operand fragments (in registers)
    unsigned wpk[4][2];
#pragma unroll
    for (int nf = 0; nf < 4; ++nf) {
      asm("v_cvt_pk_bf16_f32 %0, %1, %2" : "=v"(wpk[nf][0]) : "v"(s[nf][0]), "v"(s[nf][1]));
      asm("v_cvt_pk_bf16_f32 %0, %1, %2" : "=v"(wpk[nf][1]) : "v"(s[nf][2]), "v"(s[nf][3]));
    }
#pragma unroll
    for (int kf = 0; kf < 2; ++kf) {
      const unsigned a0w = __shfl(wpk[2 * kf][0], sl0), b0w = __shfl(wpk[2 * kf + 1][0], sl0);
      const unsigned a1w = __shfl(wpk[2 * kf][1], sl0), b1w = __shfl(wpk[2 * kf + 1][1], sl0);
      const unsigned a2w = __shfl(wpk[2 * kf][0], sl1), b2w = __shfl(wpk[2 * kf + 1][0], sl1);
      const unsigned a3w = __shfl(wpk[2 * kf][1], sl1), b3w = __shfl(wpk[2 * kf + 1][1], sl1);
      u32x4 uu;
      uu[0] = hi2 ? b0w : a0w;
      uu[1] = hi2 ? b1w : a1w;
      uu[2] = hi2 ? b2w : a2w;
      uu[3] = hi2 ? b3w : a3w;
      pap[kf] = __builtin_bit_cast(bf16x8, uu);
    }
    __syncthreads();                         // drains prefetch + guards buffers
  }

  // ---- final PV (last tile)
#pragma unroll
  for (int kf = 0; kf < 2; ++kf)
#pragma unroll
    for (int df = 0; df < 4; ++df)
      oacc[df] = __builtin_amdgcn_mfma_f32_16x16x32_bf16(vbp[kf][df], pap[kf], oacc[df], 0, 0, 0);

  float ls = lpart;
  ls += __shfl_xor(ls, 16);
  ls += __shfl_xor(ls, 32);
  const float inv = 1.f / ls;
  const int q = qb + lr;
#pragma unroll
  for (int df = 0; df < 4; ++df) {
    ushort4 o4;
    o4.x = bfc(oacc[df][0] * inv);
    o4.y = bfc(oacc[df][1] * inv);
    o4.z = bfc(oacc[df][2] * inv);
    o4.w = bfc(oacc[df][3] * inv);
    *reinterpret_cast<ushort4*>(
        &Ob[((size_t)(b * 2048 + q)) * 1024 + h * 64 + df * 16 + 4 * lg]) = o4;
  }
}

// ------------------------------------------------------------------ launch
extern "C" void kernel_launch(void* const* d_in, const int* in_sizes, int n_in,
                              void* d_out, int out_size, void* d_ws, size_t ws_size,
                              hipStream_t stream) {
  const float* x  = (const float*)d_in[0];
  const float* Wq = (const float*)d_in[1];
  const float* bq = (const float*)d_in[2];
  const float* Wk = (const float*)d_in[3];
  const float* bk = (const float*)d_in[4];
  const float* Wv = (const float*)d_in[5];
  const float* bv = (const float*)d_in[6];
  const float* Wo = (const float*)d_in[7];
  const float* bo = (const float*)d_in[8];
  float* out = (float*)d_out;

  unsigned short* xb  = (unsigned short*)d_ws;          // 4096*1024
  unsigned short* wqt = xb  + 4096 * 1024;              // 1024*1024 each
  unsigned short* wkt = wqt + 1024 * 1024;
  unsigned short* wvt = wkt + 1024 * 1024;
  unsigned short* wot = wvt + 1024 * 1024;
  unsigned short* Qh  = wot + 1024 * 1024;              // [b,h,s,d]
  unsigned short* Kh  = Qh  + 4096 * 1024;
  unsigned short* Vh  = Kh  + 4096 * 1024;              // (unused)
  unsigned short* Vt  = Vh  + 4096 * 1024;              // [b,h,d,s]
  unsigned short* Ob  = Vt  + 4096 * 1024;              // [4096][1024]

  prep_kernel<<<5120, 256, 0, stream>>>(x, Wq, Wk, Wv, Wo, xb, wqt, wkt, wvt, wot);
  gemm128<0><<<dim3(32, 24), 256, 0, stream>>>(xb, wqt, wkt, wvt, bq, bk, bv,
                                               Qh, Kh, Vt, nullptr);
  attn_kernel<<<1024, 256, 0, stream>>>(Qh, Kh, Vt, Ob);
  gemm128<1><<<dim3(32, 8), 256, 0, stream>>>(Ob, wot, nullptr, nullptr, bo, nullptr, nullptr,
                                              nullptr, nullptr, nullptr, out);
}

// Round 9
// 110.659 us; speedup vs baseline: 2.7365x; 1.0240x over previous
//
#include <hip/hip_runtime.h>

// Masked causal MHA: B=2, S=2048, E=1024, H=16, D=64.
// ws layout (bf16/ushort): xb[4096*1024] | wqt|wkt|wvt|wot[1024*1024 each, [N][K]]
//   | Qh|Kh|Vh(unused) [b,h,s,d] | Vt [b,h,d,s] | Ob [4096][1024].

using f32x4  = __attribute__((ext_vector_type(4))) float;
using bf16x8 = __attribute__((ext_vector_type(8))) __bf16;
using u16x8  = __attribute__((ext_vector_type(8))) unsigned short;
using u32x4  = __attribute__((ext_vector_type(4))) unsigned int;

__device__ __forceinline__ unsigned short f2bf(float f) {
  unsigned u = __float_as_uint(f);
  u += 0x7fff + ((u >> 16) & 1u);            // round-to-nearest-even
  return (unsigned short)(u >> 16);
}

__device__ __forceinline__ unsigned short bfc(float f) {   // HW cvt
  __bf16 h = (__bf16)f;
  return __builtin_bit_cast(unsigned short, h);
}

__device__ __forceinline__ bf16x8 ld_bf8(const unsigned short* p) {
  return __builtin_bit_cast(bf16x8, *reinterpret_cast<const u16x8*>(p));
}

#define GLDS16(gp, lp)                                                        \
  __builtin_amdgcn_global_load_lds(                                           \
      (__attribute__((address_space(1))) void*)(gp),                          \
      (__attribute__((address_space(3))) void*)(lp), 16, 0, 0)

// ------------------------------------------- prep: cast x + transpose weights
// blocks 0..4095: cast x -> bf16. blocks 4096..5119: W[k][n] -> Wt[n][k] bf16.
__global__ void prep_kernel(const float* __restrict__ x,
                            const float* __restrict__ w0, const float* __restrict__ w1,
                            const float* __restrict__ w2, const float* __restrict__ w3,
                            unsigned short* __restrict__ xb,
                            unsigned short* __restrict__ t0, unsigned short* __restrict__ t1,
                            unsigned short* __restrict__ t2, unsigned short* __restrict__ t3) {
  __shared__ float tile[64][65];
  const int t = threadIdx.x;
  const int bid = blockIdx.x;
  if (bid < 4096) {
    const int i = (bid * 256 + t) * 4;
    const float4 v = *reinterpret_cast<const float4*>(x + i);
    ushort4 o;
    o.x = f2bf(v.x); o.y = f2bf(v.y); o.z = f2bf(v.z); o.w = f2bf(v.w);
    *reinterpret_cast<ushort4*>(xb + i) = o;
    return;
  }
  const int q0 = bid - 4096;
  const int wsel = q0 >> 8, rem = q0 & 255;
  const float* src; unsigned short* dst;
  switch (wsel) {
    case 0:  src = w0; dst = t0; break;
    case 1:  src = w1; dst = t1; break;
    case 2:  src = w2; dst = t2; break;
    default: src = w3; dst = t3; break;
  }
  const int n0 = (rem & 15) * 64, k0 = (rem >> 4) * 64;
#pragma unroll
  for (int i = 0; i < 4; ++i) {               // load 64x64 fp32 tile, rows = k
    const int q = t + i * 256, r = q >> 4, c4 = q & 15;
    const float4 v = *reinterpret_cast<const float4*>(src + (k0 + r) * 1024 + n0 + c4 * 4);
    tile[r][c4 * 4 + 0] = v.x; tile[r][c4 * 4 + 1] = v.y;
    tile[r][c4 * 4 + 2] = v.z; tile[r][c4 * 4 + 3] = v.w;
  }
  __syncthreads();
#pragma unroll
  for (int i = 0; i < 4; ++i) {               // write Wt[n][k] bf16
    const int q = t + i * 256, n = q >> 4, c4 = q & 15;
    ushort4 o;
    o.x = f2bf(tile[c4 * 4 + 0][n]); o.y = f2bf(tile[c4 * 4 + 1][n]);
    o.z = f2bf(tile[c4 * 4 + 2][n]); o.w = f2bf(tile[c4 * 4 + 3][n]);
    *reinterpret_cast<ushort4*>(dst + (n0 + n) * 1024 + k0 + c4 * 4) = o;
  }
}

// ------------------------------------------------------------ QKV GEMM
// C[4096][N] = xb @ Wt^T (+ bias). 128x128 tile, BK=64, 4 waves of 64x64.
// Q scaled by 0.125*log2e -> [b,h,s,d]; K -> [b,h,s,d]; V -> Vt [b,h,d,s].
// launch_bounds(256,3): cap VGPR so 3 blocks/CU stay resident (768-block grid).
__global__ __launch_bounds__(256, 3) void gemm_qkv(
    const unsigned short* __restrict__ A,
    const unsigned short* __restrict__ BtQ, const unsigned short* __restrict__ BtK,
    const unsigned short* __restrict__ BtV,
    const float* __restrict__ biasQ, const float* __restrict__ biasK,
    const float* __restrict__ biasV,
    unsigned short* __restrict__ OQ, unsigned short* __restrict__ OK_,
    unsigned short* __restrict__ OVt) {
  __shared__ unsigned short As[128 * 64];
  __shared__ unsigned short Bs[128 * 64];

  const int mt = blockIdx.x, nt = blockIdx.y;
  const int which = nt >> 3;
  const int nloc0 = (nt & 7) * 128;
  const unsigned short* Bt = (which == 0) ? BtQ : (which == 1) ? BtK : BtV;
  const float* bias = (which == 0) ? biasQ : (which == 1) ? biasK : biasV;
  const int m0 = mt * 128;
  const int t = threadIdx.x;
  const int w = t >> 6, l = t & 63;
  const int wm = (w >> 1) * 64, wn = (w & 1) * 64;
  const int lr = l & 15, lg = l >> 4;

  f32x4 acc[4][4];
#pragma unroll
  for (int i = 0; i < 4; ++i)
#pragma unroll
    for (int j = 0; j < 4; ++j) acc[i][j] = f32x4{0.f, 0.f, 0.f, 0.f};

  for (int k0 = 0; k0 < 1024; k0 += 64) {
#pragma unroll
    for (int i = 0; i < 4; ++i) {             // stage A tile: [128 m][64 k]
      const int off = t * 16 + i * 4096;
      const int r = off >> 7, cb = off & 127;
      GLDS16(A + (m0 + r) * 1024 + k0 + (cb >> 1), ((char*)As) + off);
    }
#pragma unroll
    for (int i = 0; i < 4; ++i) {             // stage B tile: [128 n][64 k]
      const int off = t * 16 + i * 4096;
      const int r = off >> 7, cb = off & 127;
      GLDS16(Bt + (nloc0 + r) * 1024 + k0 + (cb >> 1), ((char*)Bs) + off);
    }
    __syncthreads();
#pragma unroll
    for (int kk = 0; kk < 2; ++kk) {
      bf16x8 af[4], bfr[4];
#pragma unroll
      for (int mi = 0; mi < 4; ++mi)
        af[mi] = ld_bf8(As + (wm + mi * 16 + lr) * 64 + kk * 32 + lg * 8);
#pragma unroll
      for (int ni = 0; ni < 4; ++ni)
        bfr[ni] = ld_bf8(Bs + (wn + ni * 16 + lr) * 64 + kk * 32 + lg * 8);
#pragma unroll
      for (int mi = 0; mi < 4; ++mi)
#pragma unroll
        for (int ni = 0; ni < 4; ++ni)
          acc[mi][ni] = __builtin_amdgcn_mfma_f32_16x16x32_bf16(af[mi], bfr[ni], acc[mi][ni], 0, 0, 0);
    }
    __syncthreads();
  }

  const float scl = (which == 0) ? 0.18033688f : 1.0f;   // 0.125*log2(e) for Q
#pragma unroll
  for (int ni = 0; ni < 4; ++ni) {
    const int n = nloc0 + wn + ni * 16 + lr;  // column within this weight
    const float bv = bias[n];
    const int hh = n >> 6, dd = n & 63;
#pragma unroll
    for (int mi = 0; mi < 4; ++mi) {
      const int mB = m0 + wm + mi * 16 + 4 * lg;
      const int bb = mB >> 11, sloc = mB & 2047;
      if (which == 2) {                       // V -> Vt [b,h,d,s], 8B stores
        ushort4 o4;
        o4.x = bfc(acc[mi][ni][0] + bv);
        o4.y = bfc(acc[mi][ni][1] + bv);
        o4.z = bfc(acc[mi][ni][2] + bv);
        o4.w = bfc(acc[mi][ni][3] + bv);
        *reinterpret_cast<ushort4*>(
            &OVt[(((size_t)(bb * 16 + hh)) * 64 + dd) * 2048 + sloc]) = o4;
      } else {
        unsigned short* Oqk = (which == 0) ? OQ : OK_;
#pragma unroll
        for (int r = 0; r < 4; ++r) {
          const float v = (acc[mi][ni][r] + bv) * scl;
          Oqk[(((size_t)(bb * 16 + hh)) * 2048 + sloc + r) * 64 + dd] = f2bf(v);
        }
      }
    }
  }
}

// ------------------------------------------------------- output-proj GEMM
// C[4096][1024] = Ob @ Wot^T + bo (fp32). 64x128 tile -> 512 blocks (2/CU).
__global__ __launch_bounds__(256, 2) void gemm_out(
    const unsigned short* __restrict__ A, const unsigned short* __restrict__ Bt,
    const float* __restrict__ bias, float* __restrict__ OF) {
  __shared__ unsigned short As[64 * 64];     // 8 KB
  __shared__ unsigned short Bs[128 * 64];    // 16 KB

  const int m0 = blockIdx.x * 64;
  const int nloc0 = blockIdx.y * 128;
  const int t = threadIdx.x;
  const int w = t >> 6, l = t & 63;
  const int wm = (w >> 1) * 32, wn = (w & 1) * 64;
  const int lr = l & 15, lg = l >> 4;

  f32x4 acc[2][4];
#pragma unroll
  for (int i = 0; i < 2; ++i)
#pragma unroll
    for (int j = 0; j < 4; ++j) acc[i][j] = f32x4{0.f, 0.f, 0.f, 0.f};

  for (int k0 = 0; k0 < 1024; k0 += 64) {
#pragma unroll
    for (int i = 0; i < 2; ++i) {             // stage A tile: [64 m][64 k]
      const int off = t * 16 + i * 4096;
      const int r = off >> 7, cb = off & 127;
      GLDS16(A + (m0 + r) * 1024 + k0 + (cb >> 1), ((char*)As) + off);
    }
#pragma unroll
    for (int i = 0; i < 4; ++i) {             // stage B tile: [128 n][64 k]
      const int off = t * 16 + i * 4096;
      const int r = off >> 7, cb = off & 127;
      GLDS16(Bt + (nloc0 + r) * 1024 + k0 + (cb >> 1), ((char*)Bs) + off);
    }
    __syncthreads();
#pragma unroll
    for (int kk = 0; kk < 2; ++kk) {
      bf16x8 af[2], bfr[4];
#pragma unroll
      for (int mi = 0; mi < 2; ++mi)
        af[mi] = ld_bf8(As + (wm + mi * 16 + lr) * 64 + kk * 32 + lg * 8);
#pragma unroll
      for (int ni = 0; ni < 4; ++ni)
        bfr[ni] = ld_bf8(Bs + (wn + ni * 16 + lr) * 64 + kk * 32 + lg * 8);
#pragma unroll
      for (int mi = 0; mi < 2; ++mi)
#pragma unroll
        for (int ni = 0; ni < 4; ++ni)
          acc[mi][ni] = __builtin_amdgcn_mfma_f32_16x16x32_bf16(af[mi], bfr[ni], acc[mi][ni], 0, 0, 0);
    }
    __syncthreads();
  }

#pragma unroll
  for (int ni = 0; ni < 4; ++ni) {
    const int n = nloc0 + wn + ni * 16 + lr;
    const float bv = bias[n];
#pragma unroll
    for (int mi = 0; mi < 2; ++mi) {
#pragma unroll
      for (int r = 0; r < 4; ++r) {
        const int m = m0 + wm + mi * 16 + 4 * lg + r;
        OF[m * 1024 + n] = acc[mi][ni][r] + bv;
      }
    }
  }
}

// ------------------------------------------------------- flash attention v6
// (reverted to R7-proven version) 64-row q-blocks, swapped QK^T, in-register
// softmax, defer-max, per-lane partial l. PV lags one tile via register V/P.
__global__ __launch_bounds__(256, 4) void attn_kernel(
    const unsigned short* __restrict__ Qh, const unsigned short* __restrict__ Kh,
    const unsigned short* __restrict__ Vt, unsigned short* __restrict__ Ob) {
  const int g = blockIdx.x;
  const int qt = 31 - (g >> 5);              // LPT: longest first
  const int bh = g & 31;
  const int b = bh >> 4, h = bh & 15;
  const int t = threadIdx.x, w = t >> 6, l = t & 63;
  const int lr = l & 15, lg = l >> 4;
  const int sl0 = lr + 32 * (lg & 1);        // pack-shuffle source lanes
  const int sl1 = sl0 + 16;
  const bool hi2 = (l & 32) != 0;

  __shared__ unsigned short Kb[2][4096];     // [64 kv][64 d], swizzled
  __shared__ unsigned short Vb[2][4096];     // [64 d][64 kv], swizzled

  const unsigned short* Kbase = Kh + (size_t)bh * (2048 * 64);
  const unsigned short* Vbase = Vt + (size_t)bh * (64 * 2048);

  const int qb = qt * 64 + w * 16;           // this wave's 16 q rows
  const unsigned short* Qp = Qh + ((size_t)bh * 2048 + qb + lr) * 64;
  bf16x8 qf[2];
  qf[0] = ld_bf8(Qp + lg * 8);
  qf[1] = ld_bf8(Qp + 32 + lg * 8);

  f32x4 oacc[4];                             // O^T: lane q=qb+lr, d=df*16+4lg+r
#pragma unroll
  for (int i = 0; i < 4; ++i) oacc[i] = f32x4{0.f, 0.f, 0.f, 0.f};
  float mrun = -3e38f;
  float lpart = 0.f;                         // per-lane partial denominator

  bf16x8 vbp[2][4];                          // V frags of previous tile
  bf16x8 pap[2];                             // P frags of previous tile

  auto stage = [&](int kv0, int bi) {
#pragma unroll
    for (int p = 0; p < 2; ++p) {
      const int o = t * 16 + p * 4096;       // linear byte offset in 8KB tile
      const int row = o >> 7;
      const int scb = (o & 127) ^ ((row & 7) << 4);   // pre-swizzled src col
      GLDS16(Kbase + (size_t)(kv0 + row) * 64 + (scb >> 1), ((char*)Kb[bi]) + o);
      GLDS16(Vbase + (size_t)row * 2048 + kv0 + (scb >> 1), ((char*)Vb[bi]) + o);
    }
  };

  const int nt = qt + 1;
  stage(0, 0);
  __syncthreads();

  for (int ti = 0; ti < nt; ++ti) {
    const int cur = ti & 1;
    const int kv0 = ti * 64;
    if (ti + 1 < nt) stage((ti + 1) * 64, cur ^ 1);

    // ---- QK^T (swapped: S^T = K . Q^T)
    f32x4 s[4];
#pragma unroll
    for (int i = 0; i < 4; ++i) s[i] = f32x4{0.f, 0.f, 0.f, 0.f};
    __builtin_amdgcn_s_setprio(1);
#pragma unroll
    for (int kf = 0; kf < 2; ++kf) {
#pragma unroll
      for (int nf = 0; nf < 4; ++nf) {
        const int row = nf * 16 + lr;
        const int col = (kf * 32 + lg * 8) ^ ((row & 7) << 3);
        const bf16x8 kb = ld_bf8(&Kb[cur][row * 64 + col]);
        s[nf] = __builtin_amdgcn_mfma_f32_16x16x32_bf16(kb, qf[kf], s[nf], 0, 0, 0);
      }
    }
    // ---- PV of PREVIOUS tile (register operands; overlaps softmax below)
    if (ti > 0) {
#pragma unroll
      for (int kf = 0; kf < 2; ++kf)
#pragma unroll
        for (int df = 0; df < 4; ++df)
          oacc[df] = __builtin_amdgcn_mfma_f32_16x16x32_bf16(vbp[kf][df], pap[kf], oacc[df], 0, 0, 0);
    }
    __builtin_amdgcn_s_setprio(0);

    // ---- this tile's V frags -> registers (consumed next iteration)
#pragma unroll
    for (int kf = 0; kf < 2; ++kf)
#pragma unroll
      for (int df = 0; df < 4; ++df) {
        const int vrow = df * 16 + lr;
        const int vcol = (kf * 32 + lg * 8) ^ ((vrow & 7) << 3);
        vbp[kf][df] = ld_bf8(&Vb[cur][vrow * 64 + vcol]);
      }

    // ---- softmax (no cross-lane ops on common path)
    if (ti == qt) {                          // diagonal tile: causal mask
#pragma unroll
      for (int nf = 0; nf < 4; ++nf) {
        const int kv = kv0 + nf * 16 + 4 * lg;
#pragma unroll
        for (int r = 0; r < 4; ++r)
          if (kv + r > qb + lr) s[nf][r] = -3e38f;
      }
    }
    float m01 = -3e38f, m23 = -3e38f;        // balanced per-lane max tree
#pragma unroll
    for (int r = 0; r < 4; ++r) {
      m01 = fmaxf(m01, fmaxf(s[0][r], s[1][r]));
      m23 = fmaxf(m23, fmaxf(s[2][r], s[3][r]));
    }
    const float mx = fmaxf(m01, m23);
    if (!__all(mx <= mrun + 8.f)) {          // defer-max (T13); rare branch
      float m0 = fmaxf(mx, __shfl_xor(mx, 16));
      m0 = fmaxf(m0, __shfl_xor(m0, 32));
      const float n0 = fmaxf(mrun, m0);
      const float c0 = __builtin_amdgcn_exp2f(mrun - n0);
      mrun = n0;
      lpart *= c0;
#pragma unroll
      for (int df = 0; df < 4; ++df)
#pragma unroll
        for (int r = 0; r < 4; ++r) oacc[df][r] *= c0;
    }
    float rs[4] = {0.f, 0.f, 0.f, 0.f};      // 4 independent partial sums
#pragma unroll
    for (int nf = 0; nf < 4; ++nf)
#pragma unroll
      for (int r = 0; r < 4; ++r) {
        const float p = __builtin_amdgcn_exp2f(s[nf][r] - mrun);
        s[nf][r] = p;
        rs[nf] += p;
      }
    lpart += (rs[0] + rs[1]) + (rs[2] + rs[3]);

    // ---- pack P^T into PV B-operand fragments (in registers)
    unsigned wpk[4][2];
#pragma unroll
    for (int nf = 0; nf < 4; ++nf) {
      asm("v_cvt_pk_bf16_f32 %0, %1, %2" : "=v"(wpk[nf][0]) : "v"(s[nf][0]), "v"(s[nf][1]));
      asm("v_cvt_pk_bf16_f32 %0, %1, %2" : "=v"(wpk[nf][1]) : "v"(s[nf][2]), "v"(s[nf][3]));
    }
#pragma unroll
    for (int kf = 0; kf < 2; ++kf) {
      const unsigned a0w = __shfl(wpk[2 * kf][0], sl0), b0w = __shfl(wpk[2 * kf + 1][0], sl0);
      const unsigned a1w = __shfl(wpk[2 * kf][1], sl0), b1w = __shfl(wpk[2 * kf + 1][1], sl0);
      const unsigned a2w = __shfl(wpk[2 * kf][0], sl1), b2w = __shfl(wpk[2 * kf + 1][0], sl1);
      const unsigned a3w = __shfl(wpk[2 * kf][1], sl1), b3w = __shfl(wpk[2 * kf + 1][1], sl1);
      u32x4 uu;
      uu[0] = hi2 ? b0w : a0w;
      uu[1] = hi2 ? b1w : a1w;
      uu[2] = hi2 ? b2w : a2w;
      uu[3] = hi2 ? b3w : a3w;
      pap[kf] = __builtin_bit_cast(bf16x8, uu);
    }
    __syncthreads();                         // drains prefetch + guards buffers
  }

  // ---- final PV (last tile)
#pragma unroll
  for (int kf = 0; kf < 2; ++kf)
#pragma unroll
    for (int df = 0; df < 4; ++df)
      oacc[df] = __builtin_amdgcn_mfma_f32_16x16x32_bf16(vbp[kf][df], pap[kf], oacc[df], 0, 0, 0);

  float ls = lpart;
  ls += __shfl_xor(ls, 16);
  ls += __shfl_xor(ls, 32);
  const float inv = 1.f / ls;
  const int q = qb + lr;
#pragma unroll
  for (int df = 0; df < 4; ++df) {
    ushort4 o4;
    o4.x = bfc(oacc[df][0] * inv);
    o4.y = bfc(oacc[df][1] * inv);
    o4.z = bfc(oacc[df][2] * inv);
    o4.w = bfc(oacc[df][3] * inv);
    *reinterpret_cast<ushort4*>(
        &Ob[((size_t)(b * 2048 + q)) * 1024 + h * 64 + df * 16 + 4 * lg]) = o4;
  }
}

// ------------------------------------------------------------------ launch
extern "C" void kernel_launch(void* const* d_in, const int* in_sizes, int n_in,
                              void* d_out, int out_size, void* d_ws, size_t ws_size,
                              hipStream_t stream) {
  const float* x  = (const float*)d_in[0];
  const float* Wq = (const float*)d_in[1];
  const float* bq = (const float*)d_in[2];
  const float* Wk = (const float*)d_in[3];
  const float* bk = (const float*)d_in[4];
  const float* Wv = (const float*)d_in[5];
  const float* bv = (const float*)d_in[6];
  const float* Wo = (const float*)d_in[7];
  const float* bo = (const float*)d_in[8];
  float* out = (float*)d_out;

  unsigned short* xb  = (unsigned short*)d_ws;          // 4096*1024
  unsigned short* wqt = xb  + 4096 * 1024;              // 1024*1024 each
  unsigned short* wkt = wqt + 1024 * 1024;
  unsigned short* wvt = wkt + 1024 * 1024;
  unsigned short* wot = wvt + 1024 * 1024;
  unsigned short* Qh  = wot + 1024 * 1024;              // [b,h,s,d]
  unsigned short* Kh  = Qh  + 4096 * 1024;
  unsigned short* Vh  = Kh  + 4096 * 1024;              // (unused)
  unsigned short* Vt  = Vh  + 4096 * 1024;              // [b,h,d,s]
  unsigned short* Ob  = Vt  + 4096 * 1024;              // [4096][1024]

  prep_kernel<<<5120, 256, 0, stream>>>(x, Wq, Wk, Wv, Wo, xb, wqt, wkt, wvt, wot);
  gemm_qkv<<<dim3(32, 24), 256, 0, stream>>>(xb, wqt, wkt, wvt, bq, bk, bv,
                                             Qh, Kh, Vt);
  attn_kernel<<<1024, 256, 0, stream>>>(Qh, Kh, Vt, Ob);
  gemm_out<<<dim3(64, 8), 256, 0, stream>>>(Ob, wot, bo, out);
}